// Round 1
// baseline (269.771 us; speedup 1.0000x reference)
//
#include <hip/hip_runtime.h>
#include <hip/hip_bf16.h>

using bf16 = __hip_bfloat16;
typedef __attribute__((ext_vector_type(8))) short short8;
typedef __attribute__((ext_vector_type(4))) float f32x4;

static constexpr int Bsz = 4, C = 768, T = 1024, H = 12, D = 64;

__device__ __forceinline__ f32x4 mfma16(short8 a, short8 b, f32x4 c){
  return __builtin_amdgcn_mfma_f32_16x16x32_bf16(a, b, c, 0, 0, 0);
}

__device__ __forceinline__ void gload16(const void* g, void* l){
  void* gv = const_cast<void*>(g);
  __builtin_amdgcn_global_load_lds((__attribute__((address_space(1))) void*)gv,
                                   (__attribute__((address_space(3))) void*)l, 16, 0, 0);
}

// ---- f32 -> bf16 convert (weights) ----
__global__ __launch_bounds__(256) void cvt_kernel(const float* __restrict__ in,
                                                  bf16* __restrict__ out, int n){
  int i = (blockIdx.x*256 + threadIdx.x)*4;
  if (i + 3 < n){
    float4 v = *(const float4*)(in + i);
    out[i+0] = (bf16)v.x; out[i+1] = (bf16)v.y;
    out[i+2] = (bf16)v.z; out[i+3] = (bf16)v.w;
  }
}

// ---- [B][C][T] f32 -> [B][T][C] bf16 ----
__global__ __launch_bounds__(256) void transpose_cvt(const float* __restrict__ in,
                                                     bf16* __restrict__ out){
  __shared__ float tile[64][65];
  const int b = blockIdx.z, t0 = blockIdx.x*64, c0 = blockIdx.y*64;
  const int u = threadIdx.x & 63, r0 = threadIdx.x >> 6;
  const float* ip = in + ((size_t)b*C + c0)*T + t0;
  #pragma unroll
  for (int i = r0; i < 64; i += 4) tile[i][u] = ip[(size_t)i*T + u];
  __syncthreads();
  bf16* op = out + ((size_t)b*T + t0)*C + c0;
  #pragma unroll
  for (int j = r0; j < 64; j += 4) op[(size_t)j*C + u] = (bf16)tile[u][j];
}

// ---- GEMM: C[m][n] = sum_k A[m][k]*B[n][k], 128x128 tile, BK=32 ----
// MODE 0: Q proj  (A=xb[b] [T][C], B=Wq, out q_ws [B,H,T,64], (v+bias)*0.125)
// MODE 1: K proj  (A=cb[b],        B=Wk, out k_ws [B,H,T,64], v+bias)
// MODE 2: V proj  (A=Wv,  B=cb[b], out v_ws [B,C,T] bf16, v+bias)
// MODE 3: O proj  (A=Wo,  B=attn[b] [T][C], out d_out [B,C,T] f32, v+bias)
template<int MODE>
__global__ __launch_bounds__(256) void gemm_bt(const bf16* __restrict__ Aab,
                                               const bf16* __restrict__ Bab,
                                               const float* __restrict__ bias,
                                               void* __restrict__ outp, float scale){
  const int tid = threadIdx.x, lane = tid & 63, w = tid >> 6;
  const int wr = w >> 1, wc = w & 1, g = lane >> 4, cl = lane & 15;
  const int b = blockIdx.z;
  const int m0 = blockIdx.x*128, n0 = blockIdx.y*128;
  const bf16* A  = (MODE <= 1) ? Aab + (size_t)b*T*C : Aab;
  const bf16* Bp = (MODE <= 1) ? Bab : Bab + (size_t)b*T*C;
  __shared__ bf16 lA[128*32], lB[128*32];
  f32x4 acc[4][4] = {};
  const bf16* Ars = A  + (size_t)m0*768;
  const bf16* Brs = Bp + (size_t)n0*768;
  for (int k0 = 0; k0 < 768; k0 += 32){
    __syncthreads();
    #pragma unroll
    for (int r = 0; r < 2; ++r){
      int t2 = r*256 + tid;
      int row = t2 >> 2, col = (t2 & 3)*8;
      gload16(Ars + (size_t)row*768 + k0 + col, &lA[(size_t)(r*256 + w*64)*8]);
      gload16(Brs + (size_t)row*768 + k0 + col, &lB[(size_t)(r*256 + w*64)*8]);
    }
    __syncthreads();
    short8 af[4], bfr[4];
    #pragma unroll
    for (int mi = 0; mi < 4; ++mi) af[mi]  = *(const short8*)&lA[(wr*64 + mi*16 + cl)*32 + g*8];
    #pragma unroll
    for (int ni = 0; ni < 4; ++ni) bfr[ni] = *(const short8*)&lB[(wc*64 + ni*16 + cl)*32 + g*8];
    #pragma unroll
    for (int mi = 0; mi < 4; ++mi)
      #pragma unroll
      for (int ni = 0; ni < 4; ++ni)
        acc[mi][ni] = mfma16(af[mi], bfr[ni], acc[mi][ni]);
  }
  #pragma unroll
  for (int mi = 0; mi < 4; ++mi){
    const int mB = m0 + wr*64 + mi*16 + g*4;
    #pragma unroll
    for (int ni = 0; ni < 4; ++ni){
      const int n = n0 + wc*64 + ni*16 + cl;
      #pragma unroll
      for (int r = 0; r < 4; ++r){
        const int m = mB + r;
        float v = acc[mi][ni][r];
        if (MODE <= 1){
          v = (v + bias[n]) * scale;
          ((bf16*)outp)[(size_t)b*(H*T*D) + (size_t)(n >> 6)*(T*D) + (size_t)m*D + (n & 63)] = (bf16)v;
        } else if (MODE == 2){
          v += bias[m];
          ((bf16*)outp)[(size_t)b*(C*T) + (size_t)m*T + n] = (bf16)v;
        } else {
          v += bias[m];
          ((float*)outp)[(size_t)b*(C*T) + (size_t)m*T + n] = v;
        }
      }
    }
  }
}

// ---- fused attention: QK^T + band rel-k + proximal bias + online softmax
//      + PV + band rel-v.  Q-tile 64 rows, stream 16 j-tiles of 64. ----
__global__ __launch_bounds__(256) void attn_kernel(const bf16* __restrict__ qws,
                                                   const bf16* __restrict__ kws,
                                                   const bf16* __restrict__ vws,
                                                   bf16* __restrict__ aws,
                                                   const float* __restrict__ relk,
                                                   const float* __restrict__ relv){
  const int tid = threadIdx.x, lane = tid & 63, w = tid >> 6;
  const int g = lane >> 4, cl = lane & 15;
  const int i0 = blockIdx.x*64, bh = blockIdx.y;
  const int b = bh / H, h = bh % H;

  __shared__ bf16 lQ[64*64], lK[64*64], lV[64*64], lP[64*64];
  __shared__ float relk_dot[64*21], bandS[64*21], lEmb[21*64], logtab[1024];
  __shared__ float m_lds[64], l_lds[64];

  const bf16* qg = qws + ((size_t)bh*T + i0)*D;
  const bf16* kg = kws + (size_t)bh*T*D;
  const bf16* vg = vws + ((size_t)b*C + h*D)*T;

  #pragma unroll
  for (int r = 0; r < 2; ++r)
    gload16(qg + (size_t)(r*256 + tid)*8, &lQ[(size_t)(r*256 + w*64)*8]);
  for (int idx = tid; idx < 1024; idx += 256) logtab[idx] = __logf(1.0f + (float)idx);
  for (int idx = tid; idx < 21*64; idx += 256) lEmb[idx] = relk[idx];
  __syncthreads();

  // per-row dot of scaled-Q with each of the 21 rel-k embeddings
  for (int p = tid; p < 64*21; p += 256){
    const int i = p / 21, r = p - i*21;
    float s = 0.f;
    for (int kk = 0; kk < 64; ++kk) s += (float)lQ[i*64 + kk] * lEmb[r*64 + kk];
    relk_dot[p] = s;
  }
  const short8 aq0 = *(const short8*)&lQ[(w*16 + cl)*64 + g*8];
  const short8 aq1 = *(const short8*)&lQ[(w*16 + cl)*64 + 32 + g*8];

  float mreg[4] = {-1e30f, -1e30f, -1e30f, -1e30f};
  float lreg[4] = {0.f, 0.f, 0.f, 0.f};
  f32x4 o[4] = {};

  for (int jt = 0; jt < 16; ++jt){
    const int j0 = jt*64;
    __syncthreads();
    #pragma unroll
    for (int r = 0; r < 2; ++r){
      const int t2 = r*256 + tid;
      gload16(kg + (size_t)(j0 + (t2 >> 3))*D + (t2 & 7)*8, &lK[(size_t)(r*256 + w*64)*8]);
      gload16(vg + (size_t)(t2 >> 3)*T + j0 + (t2 & 7)*8,   &lV[(size_t)(r*256 + w*64)*8]);
    }
    __syncthreads();

    f32x4 s[4] = {};
    #pragma unroll
    for (int ni = 0; ni < 4; ++ni){
      short8 b0 = *(const short8*)&lK[(ni*16 + cl)*64 + g*8];
      s[ni] = mfma16(aq0, b0, s[ni]);
      short8 b1 = *(const short8*)&lK[(ni*16 + cl)*64 + 32 + g*8];
      s[ni] = mfma16(aq1, b1, s[ni]);
    }

    const int ib = w*16 + g*4;
    #pragma unroll
    for (int ni = 0; ni < 4; ++ni){
      const int j = j0 + ni*16 + cl;
      #pragma unroll
      for (int r = 0; r < 4; ++r){
        const int dd = j - (i0 + ib + r);
        const int ad = dd < 0 ? -dd : dd;
        float v = s[ni][r] - logtab[ad];
        if (ad <= 10){
          v += relk_dot[(ib + r)*21 + dd + 10];
          bandS[(ib + r)*21 + dd + 10] = v;   // raw score for exact band-p later
        }
        s[ni][r] = v;
      }
    }

    #pragma unroll
    for (int r = 0; r < 4; ++r){
      float v = fmaxf(fmaxf(s[0][r], s[1][r]), fmaxf(s[2][r], s[3][r]));
      v = fmaxf(v, __shfl_xor(v, 1));
      v = fmaxf(v, __shfl_xor(v, 2));
      v = fmaxf(v, __shfl_xor(v, 4));
      v = fmaxf(v, __shfl_xor(v, 8));
      const float mn = fmaxf(mreg[r], v);
      const float sc = __expf(mreg[r] - mn);
      mreg[r] = mn;
      float rs = 0.f;
      #pragma unroll
      for (int ni = 0; ni < 4; ++ni){
        float p = __expf(s[ni][r] - mn);
        s[ni][r] = p; rs += p;
      }
      rs += __shfl_xor(rs, 1); rs += __shfl_xor(rs, 2);
      rs += __shfl_xor(rs, 4); rs += __shfl_xor(rs, 8);
      lreg[r] = lreg[r]*sc + rs;
      o[0][r] *= sc; o[1][r] *= sc; o[2][r] *= sc; o[3][r] *= sc;
      #pragma unroll
      for (int ni = 0; ni < 4; ++ni)
        lP[(ib + r)*64 + ni*16 + cl] = (bf16)s[ni][r];
    }

    const short8 ap0 = *(const short8*)&lP[(w*16 + cl)*64 + g*8];
    const short8 ap1 = *(const short8*)&lP[(w*16 + cl)*64 + 32 + g*8];
    #pragma unroll
    for (int ni = 0; ni < 4; ++ni){
      short8 b0 = *(const short8*)&lV[(ni*16 + cl)*64 + g*8];
      o[ni] = mfma16(ap0, b0, o[ni]);
      short8 b1 = *(const short8*)&lV[(ni*16 + cl)*64 + 32 + g*8];
      o[ni] = mfma16(ap1, b1, o[ni]);
    }
  }

  if (cl == 0){
    #pragma unroll
    for (int r = 0; r < 4; ++r){
      m_lds[w*16 + g*4 + r] = mreg[r];
      l_lds[w*16 + g*4 + r] = lreg[r];
    }
  }
  __syncthreads();
  for (int idx = tid; idx < 21*64; idx += 256) lEmb[idx] = relv[idx];
  for (int p = tid; p < 64*21; p += 256){
    const int i = p / 21, r = p - i*21;
    const int j = i0 + i + r - 10;
    float bp = 0.f;
    if (j >= 0 && j < T) bp = __expf(bandS[p] - m_lds[i]) / l_lds[i];
    bandS[p] = bp;                           // now holds band probabilities
  }
  __syncthreads();

  const int ib = w*16 + g*4;
  float invl[4];
  #pragma unroll
  for (int r = 0; r < 4; ++r) invl[r] = 1.0f / lreg[r];
  #pragma unroll
  for (int ni = 0; ni < 4; ++ni){
    const int dcol = ni*16 + cl;
    #pragma unroll
    for (int r = 0; r < 4; ++r){
      float v = o[ni][r] * invl[r];
      float add = 0.f;
      #pragma unroll
      for (int rr = 0; rr < 21; ++rr)
        add += bandS[(ib + r)*21 + rr] * lEmb[rr*64 + dcol];
      aws[((size_t)(b*T + i0 + ib + r))*C + h*D + dcol] = (bf16)(v + add);
    }
  }
}

extern "C" void kernel_launch(void* const* d_in, const int* in_sizes, int n_in,
                              void* d_out, int out_size, void* d_ws, size_t ws_size,
                              hipStream_t stream){
  const float* x    = (const float*)d_in[0];
  const float* cin  = (const float*)d_in[1];
  const float* Wq   = (const float*)d_in[2];
  const float* bq   = (const float*)d_in[3];
  const float* Wk   = (const float*)d_in[4];
  const float* bk   = (const float*)d_in[5];
  const float* Wv   = (const float*)d_in[6];
  const float* bv   = (const float*)d_in[7];
  const float* Wo   = (const float*)d_in[8];
  const float* bo   = (const float*)d_in[9];
  const float* relk = (const float*)d_in[10];
  const float* relv = (const float*)d_in[11];

  char* ws = (char*)d_ws;
  constexpr size_t SZ_W = (size_t)768*768*2;     // bf16 weight matrix
  constexpr size_t SZ_T = (size_t)4*1024*768*2;  // bf16 [B,T,C]-sized tensor
  bf16* wq  = (bf16*)(ws + 0*SZ_W);
  bf16* wk  = (bf16*)(ws + 1*SZ_W);
  bf16* wv  = (bf16*)(ws + 2*SZ_W);
  bf16* wo  = (bf16*)(ws + 3*SZ_W);
  bf16* xb  = (bf16*)(ws + 4*SZ_W);
  bf16* cb  = (bf16*)(ws + 4*SZ_W + 1*SZ_T);
  bf16* qws = (bf16*)(ws + 4*SZ_W + 2*SZ_T);
  bf16* kws = (bf16*)(ws + 4*SZ_W + 3*SZ_T);
  bf16* vws = (bf16*)(ws + 4*SZ_W + 4*SZ_T);
  bf16* attn = xb;   // alias: xb is dead after the Q projection

  cvt_kernel<<<576, 256, 0, stream>>>(Wq, wq, 768*768);
  cvt_kernel<<<576, 256, 0, stream>>>(Wk, wk, 768*768);
  cvt_kernel<<<576, 256, 0, stream>>>(Wv, wv, 768*768);
  cvt_kernel<<<576, 256, 0, stream>>>(Wo, wo, 768*768);
  transpose_cvt<<<dim3(16,12,4), 256, 0, stream>>>(x,   xb);
  transpose_cvt<<<dim3(16,12,4), 256, 0, stream>>>(cin, cb);
  gemm_bt<0><<<dim3(8,6,4), 256, 0, stream>>>(xb, wq, bq, qws, 0.125f);
  gemm_bt<1><<<dim3(8,6,4), 256, 0, stream>>>(cb, wk, bk, kws, 1.0f);
  gemm_bt<2><<<dim3(6,8,4), 256, 0, stream>>>(wv, cb, bv, vws, 1.0f);
  attn_kernel<<<dim3(16,48), 256, 0, stream>>>(qws, kws, vws, attn, relk, relv);
  gemm_bt<3><<<dim3(6,8,4), 256, 0, stream>>>(wo, attn, bo, d_out, 1.0f);
}

// Round 2
// 172.690 us; speedup vs baseline: 1.5622x; 1.5622x over previous
//
#include <hip/hip_runtime.h>
#include <hip/hip_bf16.h>

using bf16 = __hip_bfloat16;
typedef __attribute__((ext_vector_type(8))) short short8;
typedef __attribute__((ext_vector_type(4))) float f32x4;

static constexpr int Bsz = 4, C = 768, T = 1024, H = 12, D = 64;

__device__ __forceinline__ f32x4 mfma16(short8 a, short8 b, f32x4 c){
  return __builtin_amdgcn_mfma_f32_16x16x32_bf16(a, b, c, 0, 0, 0);
}

__device__ __forceinline__ void gload16(const void* g, void* l){
  void* gv = const_cast<void*>(g);
  __builtin_amdgcn_global_load_lds((__attribute__((address_space(1))) void*)gv,
                                   (__attribute__((address_space(3))) void*)l, 16, 0, 0);
}

__device__ __forceinline__ float b2f(short s){
  unsigned u = ((unsigned)(unsigned short)s) << 16;
  return __builtin_bit_cast(float, u);
}

// ---- 4x f32 -> bf16 weight convert, fused ----
__global__ __launch_bounds__(256) void cvt4_kernel(const float* __restrict__ a,
                                                   const float* __restrict__ b,
                                                   const float* __restrict__ c_,
                                                   const float* __restrict__ d,
                                                   bf16* oa, bf16* ob, bf16* oc, bf16* od){
  const int m = blockIdx.y;
  const float* in = m==0 ? a : m==1 ? b : m==2 ? c_ : d;
  bf16* out = m==0 ? oa : m==1 ? ob : m==2 ? oc : od;
  int i = (blockIdx.x*256 + threadIdx.x)*4;   // 576*256*4 == 768*768 exactly
  float4 v = *(const float4*)(in + i);
  out[i+0] = (bf16)v.x; out[i+1] = (bf16)v.y;
  out[i+2] = (bf16)v.z; out[i+3] = (bf16)v.w;
}

// ---- [B][C][T] f32 -> [B][T][C] bf16 ----
__global__ __launch_bounds__(256) void transpose_cvt(const float* __restrict__ in,
                                                     bf16* __restrict__ out){
  __shared__ float tile[64][65];
  const int b = blockIdx.z, t0 = blockIdx.x*64, c0 = blockIdx.y*64;
  const int u = threadIdx.x & 63, r0 = threadIdx.x >> 6;
  const float* ip = in + ((size_t)b*C + c0)*T + t0;
  #pragma unroll
  for (int i = r0; i < 64; i += 4) tile[i][u] = ip[(size_t)i*T + u];
  __syncthreads();
  bf16* op = out + ((size_t)b*T + t0)*C + c0;
  #pragma unroll
  for (int j = r0; j < 64; j += 4) op[(size_t)j*C + u] = (bf16)tile[u][j];
}

// ---- GEMM: C[m][n] = sum_k A[m][k]*B[n][k], 128x128 tile, BK=64, swizzled LDS ----
// MODE 0: Q proj  (A=xb[b] [T][C], B=Wq, out q_ws [B,H,T,64], (v+bias)*0.125)
// MODE 1: K proj  (A=cb[b],        B=Wk, out k_ws [B,H,T,64], v+bias)
// MODE 2: V proj  (A=Wv,  B=cb[b], out v_ws [B,C,T] bf16, v+bias)
// MODE 3: O proj  (A=Wo,  B=attn[b] [T][C], out d_out [B,C,T] f32, v+bias)
template<int MODE>
__global__ __launch_bounds__(256,3) void gemm_bt(const bf16* __restrict__ Aab,
                                                 const bf16* __restrict__ Bab,
                                                 const float* __restrict__ bias,
                                                 void* __restrict__ outp, float scale){
  const int tid = threadIdx.x, lane = tid & 63, w = tid >> 6;
  const int wr = w >> 1, wc = w & 1, g = lane >> 4, cl = lane & 15;
  const int b = blockIdx.z;
  const int m0 = blockIdx.x*128, n0 = blockIdx.y*128;
  const bf16* A  = (MODE <= 1) ? Aab + (size_t)b*T*C : Aab;
  const bf16* Bp = (MODE <= 1) ? Bab : Bab + (size_t)b*T*C;
  __shared__ bf16 lA[128*64], lB[128*64];
  f32x4 acc[4][4] = {};
  const bf16* Ars = A  + (size_t)m0*768;
  const bf16* Brs = Bp + (size_t)n0*768;
  for (int k0 = 0; k0 < 768; k0 += 64){
    __syncthreads();
    #pragma unroll
    for (int rr = 0; rr < 4; ++rr){
      const int u = rr*256 + tid;           // chunk index: row=u>>3, c=u&7
      const int row = u >> 3, cc = u & 7;
      const int src = row*768 + k0 + ((cc ^ (row & 7))*8);   // pre-swizzled source
      gload16(Ars + src, &lA[(size_t)u*8]);
      gload16(Brs + src, &lB[(size_t)u*8]);
    }
    __syncthreads();
    #pragma unroll
    for (int kh = 0; kh < 2; ++kh){
      short8 af[4], bfr[4];
      #pragma unroll
      for (int mi = 0; mi < 4; ++mi){
        const int row = wr*64 + mi*16 + cl;
        af[mi] = *(const short8*)&lA[row*64 + (((g + kh*4) ^ (row & 7))*8)];
      }
      #pragma unroll
      for (int ni = 0; ni < 4; ++ni){
        const int row = wc*64 + ni*16 + cl;
        bfr[ni] = *(const short8*)&lB[row*64 + (((g + kh*4) ^ (row & 7))*8)];
      }
      #pragma unroll
      for (int mi = 0; mi < 4; ++mi)
        #pragma unroll
        for (int ni = 0; ni < 4; ++ni)
          acc[mi][ni] = mfma16(af[mi], bfr[ni], acc[mi][ni]);
    }
  }
  #pragma unroll
  for (int mi = 0; mi < 4; ++mi){
    const int mB = m0 + wr*64 + mi*16 + g*4;
    #pragma unroll
    for (int ni = 0; ni < 4; ++ni){
      const int n = n0 + wc*64 + ni*16 + cl;
      #pragma unroll
      for (int r = 0; r < 4; ++r){
        const int m = mB + r;
        float v = acc[mi][ni][r];
        if (MODE <= 1){
          v = (v + bias[n]) * scale;
          ((bf16*)outp)[(size_t)b*(H*T*D) + (size_t)(n >> 6)*(T*D) + (size_t)m*D + (n & 63)] = (bf16)v;
        } else if (MODE == 2){
          v += bias[m];
          ((bf16*)outp)[(size_t)b*(C*T) + (size_t)m*T + n] = (bf16)v;
        } else {
          v += bias[m];
          ((float*)outp)[(size_t)b*(C*T) + (size_t)m*T + n] = v;
        }
      }
    }
  }
}

// ---- fused attention: QK^T + band rel-k + proximal bias + online softmax
//      + PV + band rel-v.  Q-tile 64 rows, stream 16 j-tiles of 64.
//      All 64-col bf16 LDS tiles chunk-swizzled: chunk c -> c ^ (row&7). ----
__global__ __launch_bounds__(256,3) void attn_kernel(const bf16* __restrict__ qws,
                                                     const bf16* __restrict__ kws,
                                                     const bf16* __restrict__ vws,
                                                     bf16* __restrict__ aws,
                                                     const float* __restrict__ relk,
                                                     const float* __restrict__ relv){
  const int tid = threadIdx.x, lane = tid & 63, w = tid >> 6;
  const int g = lane >> 4, cl = lane & 15;
  const int i0 = blockIdx.x*64, bh = blockIdx.y;
  const int b = bh / H, h = bh % H;

  __shared__ bf16 lQ[64*64], lK[64*64], lV[64*64], lP[64*64];
  __shared__ float relk_dot[64*21], bandS[64*21], logtab[1024];
  __shared__ bf16 lEmbH[21*72];            // padded rows: 144B = 9 banks offset
  __shared__ float m_lds[64], l_lds[64];

  const bf16* qg = qws + ((size_t)bh*T + i0)*D;
  const bf16* kg = kws + (size_t)bh*T*D;
  const bf16* vg = vws + ((size_t)b*C + h*D)*T;

  #pragma unroll
  for (int r = 0; r < 2; ++r){
    const int u = r*256 + tid, row = u >> 3, cc = u & 7;
    gload16(qg + row*64 + ((cc ^ (row & 7))*8), &lQ[(size_t)u*8]);
  }
  for (int idx = tid; idx < 1024; idx += 256) logtab[idx] = __logf(1.0f + (float)idx);
  for (int idx = tid; idx < 21*64; idx += 256) lEmbH[(idx/64)*72 + (idx&63)] = (bf16)relk[idx];
  __syncthreads();

  // per-row dot of scaled-Q with each of the 21 rel-k embeddings (vectorized)
  for (int p = tid; p < 64*21; p += 256){
    const int i = p / 21, r = p - i*21;
    float s = 0.f;
    #pragma unroll
    for (int c2 = 0; c2 < 8; ++c2){
      short8 qv = *(const short8*)&lQ[i*64 + ((c2 ^ (i & 7))*8)];
      short8 ev = *(const short8*)&lEmbH[r*72 + c2*8];
      #pragma unroll
      for (int e = 0; e < 8; ++e) s += b2f(qv[e]) * b2f(ev[e]);
    }
    relk_dot[p] = s;
  }
  const int qrow = w*16 + cl;
  const short8 aq0 = *(const short8*)&lQ[qrow*64 + ((g ^ (qrow & 7))*8)];
  const short8 aq1 = *(const short8*)&lQ[qrow*64 + (((g + 4) ^ (qrow & 7))*8)];

  float mreg[4] = {-1e30f, -1e30f, -1e30f, -1e30f};
  float lreg[4] = {0.f, 0.f, 0.f, 0.f};
  f32x4 o[4] = {};

  for (int jt = 0; jt < 16; ++jt){
    const int j0 = jt*64;
    __syncthreads();
    #pragma unroll
    for (int r = 0; r < 2; ++r){
      const int u = r*256 + tid, row = u >> 3, cc = u & 7;
      const int sc = (cc ^ (row & 7))*8;
      gload16(kg + (size_t)(j0 + row)*D + sc, &lK[(size_t)u*8]);
      gload16(vg + (size_t)row*T + j0 + sc,   &lV[(size_t)u*8]);
    }
    __syncthreads();

    f32x4 s[4] = {};
    #pragma unroll
    for (int ni = 0; ni < 4; ++ni){
      const int row = ni*16 + cl;
      short8 b0 = *(const short8*)&lK[row*64 + ((g ^ (row & 7))*8)];
      s[ni] = mfma16(aq0, b0, s[ni]);
      short8 b1 = *(const short8*)&lK[row*64 + (((g + 4) ^ (row & 7))*8)];
      s[ni] = mfma16(aq1, b1, s[ni]);
    }

    const int ib = w*16 + g*4;
    #pragma unroll
    for (int ni = 0; ni < 4; ++ni){
      const int j = j0 + ni*16 + cl;
      #pragma unroll
      for (int r = 0; r < 4; ++r){
        const int dd = j - (i0 + ib + r);
        const int ad = dd < 0 ? -dd : dd;
        float v = s[ni][r] - logtab[ad];
        if (ad <= 10){
          v += relk_dot[(ib + r)*21 + dd + 10];
          bandS[(ib + r)*21 + dd + 10] = v;   // raw score for exact band-p later
        }
        s[ni][r] = v;
      }
    }

    #pragma unroll
    for (int r = 0; r < 4; ++r){
      float v = fmaxf(fmaxf(s[0][r], s[1][r]), fmaxf(s[2][r], s[3][r]));
      v = fmaxf(v, __shfl_xor(v, 1));
      v = fmaxf(v, __shfl_xor(v, 2));
      v = fmaxf(v, __shfl_xor(v, 4));
      v = fmaxf(v, __shfl_xor(v, 8));
      const float mn = fmaxf(mreg[r], v);
      const float sc = __expf(mreg[r] - mn);
      mreg[r] = mn;
      float rs = 0.f;
      #pragma unroll
      for (int ni = 0; ni < 4; ++ni){
        float p = __expf(s[ni][r] - mn);
        s[ni][r] = p; rs += p;
      }
      rs += __shfl_xor(rs, 1); rs += __shfl_xor(rs, 2);
      rs += __shfl_xor(rs, 4); rs += __shfl_xor(rs, 8);
      lreg[r] = lreg[r]*sc + rs;
      o[0][r] *= sc; o[1][r] *= sc; o[2][r] *= sc; o[3][r] *= sc;
      const int prow = ib + r, pm = (prow & 7) << 3;
      #pragma unroll
      for (int ni = 0; ni < 4; ++ni)
        lP[prow*64 + ((ni*16 + cl) ^ pm)] = (bf16)s[ni][r];
    }

    const short8 ap0 = *(const short8*)&lP[qrow*64 + ((g ^ (qrow & 7))*8)];
    const short8 ap1 = *(const short8*)&lP[qrow*64 + (((g + 4) ^ (qrow & 7))*8)];
    #pragma unroll
    for (int ni = 0; ni < 4; ++ni){
      const int row = ni*16 + cl;
      short8 b0 = *(const short8*)&lV[row*64 + ((g ^ (row & 7))*8)];
      o[ni] = mfma16(ap0, b0, o[ni]);
      short8 b1 = *(const short8*)&lV[row*64 + (((g + 4) ^ (row & 7))*8)];
      o[ni] = mfma16(ap1, b1, o[ni]);
    }
  }

  if (cl == 0){
    #pragma unroll
    for (int r = 0; r < 4; ++r){
      m_lds[w*16 + g*4 + r] = mreg[r];
      l_lds[w*16 + g*4 + r] = lreg[r];
    }
  }
  __syncthreads();
  for (int idx = tid; idx < 21*64; idx += 256) lEmbH[(idx/64)*72 + (idx&63)] = (bf16)relv[idx];
  for (int p = tid; p < 64*21; p += 256){
    const int i = p / 21, r = p - i*21;
    const int j = i0 + i + r - 10;
    float bp = 0.f;
    if (j >= 0 && j < T) bp = __expf(bandS[p] - m_lds[i]) / l_lds[i];
    bandS[p] = bp;                           // now holds band probabilities
  }
  __syncthreads();

  const int ib = w*16 + g*4;
  float invl[4];
  #pragma unroll
  for (int r = 0; r < 4; ++r) invl[r] = 1.0f / lreg[r];
  #pragma unroll
  for (int ni = 0; ni < 4; ++ni){
    const int dcol = ni*16 + cl;
    #pragma unroll
    for (int r = 0; r < 4; ++r){
      float v = o[ni][r] * invl[r];
      float add = 0.f;
      #pragma unroll
      for (int rr = 0; rr < 21; ++rr)
        add += bandS[(ib + r)*21 + rr] * b2f(*(const short*)&lEmbH[rr*72 + dcol]);
      aws[((size_t)(b*T + i0 + ib + r))*C + h*D + dcol] = (bf16)(v + add);
    }
  }
}

extern "C" void kernel_launch(void* const* d_in, const int* in_sizes, int n_in,
                              void* d_out, int out_size, void* d_ws, size_t ws_size,
                              hipStream_t stream){
  const float* x    = (const float*)d_in[0];
  const float* cin  = (const float*)d_in[1];
  const float* Wq   = (const float*)d_in[2];
  const float* bq   = (const float*)d_in[3];
  const float* Wk   = (const float*)d_in[4];
  const float* bk   = (const float*)d_in[5];
  const float* Wv   = (const float*)d_in[6];
  const float* bv   = (const float*)d_in[7];
  const float* Wo   = (const float*)d_in[8];
  const float* bo   = (const float*)d_in[9];
  const float* relk = (const float*)d_in[10];
  const float* relv = (const float*)d_in[11];

  char* ws = (char*)d_ws;
  constexpr size_t SZ_W = (size_t)768*768*2;     // bf16 weight matrix
  constexpr size_t SZ_T = (size_t)4*1024*768*2;  // bf16 [B,T,C]-sized tensor
  bf16* wq  = (bf16*)(ws + 0*SZ_W);
  bf16* wk  = (bf16*)(ws + 1*SZ_W);
  bf16* wv  = (bf16*)(ws + 2*SZ_W);
  bf16* wo  = (bf16*)(ws + 3*SZ_W);
  bf16* xb  = (bf16*)(ws + 4*SZ_W);
  bf16* cb  = (bf16*)(ws + 4*SZ_W + 1*SZ_T);
  bf16* qws = (bf16*)(ws + 4*SZ_W + 2*SZ_T);
  bf16* kws = (bf16*)(ws + 4*SZ_W + 3*SZ_T);
  bf16* vws = (bf16*)(ws + 4*SZ_W + 4*SZ_T);
  bf16* attn = xb;   // alias: xb is dead after the Q projection

  cvt4_kernel<<<dim3(576,4), 256, 0, stream>>>(Wq, Wk, Wv, Wo, wq, wk, wv, wo);
  transpose_cvt<<<dim3(16,12,4), 256, 0, stream>>>(x,   xb);
  transpose_cvt<<<dim3(16,12,4), 256, 0, stream>>>(cin, cb);
  gemm_bt<0><<<dim3(8,6,4), 256, 0, stream>>>(xb, wq, bq, qws, 0.125f);
  gemm_bt<1><<<dim3(8,6,4), 256, 0, stream>>>(cb, wk, bk, kws, 1.0f);
  gemm_bt<2><<<dim3(6,8,4), 256, 0, stream>>>(wv, cb, bv, vws, 1.0f);
  attn_kernel<<<dim3(16,48), 256, 0, stream>>>(qws, kws, vws, attn, relk, relv);
  gemm_bt<3><<<dim3(6,8,4), 256, 0, stream>>>(wo, attn, bo, d_out, 1.0f);
}

// Round 4
// 140.592 us; speedup vs baseline: 1.9188x; 1.2283x over previous
//
#include <hip/hip_runtime.h>
#include <hip/hip_bf16.h>
#include <hip/hip_fp16.h>

using bf16 = __hip_bfloat16;
typedef __attribute__((ext_vector_type(8))) short short8;
typedef __attribute__((ext_vector_type(4))) float f32x4;

static constexpr int C = 768, T = 1024, H = 12, D = 64;

__device__ __forceinline__ f32x4 mfma16(short8 a, short8 b, f32x4 c){
  return __builtin_amdgcn_mfma_f32_16x16x32_bf16(a, b, c, 0, 0, 0);
}

__device__ __forceinline__ void gload16(const void* g, void* l){
  void* gv = const_cast<void*>(g);
  __builtin_amdgcn_global_load_lds((__attribute__((address_space(1))) void*)gv,
                                   (__attribute__((address_space(3))) void*)l, 16, 0, 0);
}

__device__ __forceinline__ float b2f(short s){
  unsigned u = ((unsigned)(unsigned short)s) << 16;
  return __builtin_bit_cast(float, u);
}

template<int N>
__device__ __forceinline__ float row_ror(float v){
  return __builtin_bit_cast(float, __builtin_amdgcn_update_dpp(
      0, __builtin_bit_cast(int, v), 0x120 | N, 0xF, 0xF, false));
}
__device__ __forceinline__ float rmax16(float v){
  v = fmaxf(v, row_ror<8>(v)); v = fmaxf(v, row_ror<4>(v));
  v = fmaxf(v, row_ror<2>(v)); v = fmaxf(v, row_ror<1>(v)); return v;
}
__device__ __forceinline__ float rsum16(float v){
  v += row_ror<8>(v); v += row_ror<4>(v);
  v += row_ror<2>(v); v += row_ror<1>(v); return v;
}

// ---- 4x f32 -> bf16 weight convert, fused ----
__global__ __launch_bounds__(256) void cvt4_kernel(const float* __restrict__ a,
                                                   const float* __restrict__ b,
                                                   const float* __restrict__ c_,
                                                   const float* __restrict__ d,
                                                   bf16* oa, bf16* ob, bf16* oc, bf16* od){
  const int m = blockIdx.y;
  const float* in = m==0 ? a : m==1 ? b : m==2 ? c_ : d;
  bf16* out = m==0 ? oa : m==1 ? ob : m==2 ? oc : od;
  int i = (blockIdx.x*256 + threadIdx.x)*4;
  float4 v = *(const float4*)(in + i);
  out[i+0] = (bf16)v.x; out[i+1] = (bf16)v.y;
  out[i+2] = (bf16)v.z; out[i+3] = (bf16)v.w;
}

// ---- [B][C][T] f32 -> [B][T][C] bf16, both tensors in one launch ----
__global__ __launch_bounds__(256) void transpose_cvt2(const float* __restrict__ xin,
                                                      const float* __restrict__ cin,
                                                      bf16* __restrict__ xo,
                                                      bf16* __restrict__ co){
  __shared__ float tile[64][65];
  const int z = blockIdx.z, b = z & 3, which = z >> 2;
  const float* in = which ? cin : xin;
  bf16* out = which ? co : xo;
  const int t0 = blockIdx.x*64, c0 = blockIdx.y*64;
  const int u = threadIdx.x & 63, r0 = threadIdx.x >> 6;
  const float* ip = in + ((size_t)b*C + c0)*T + t0;
  #pragma unroll
  for (int i = r0; i < 64; i += 4) tile[i][u] = ip[(size_t)i*T + u];
  __syncthreads();
  bf16* op = out + ((size_t)b*T + t0)*C + c0;
  #pragma unroll
  for (int j = r0; j < 64; j += 4) op[(size_t)j*C + u] = (bf16)tile[u][j];
}

// ---- merged Q/K/V projection GEMM: 128x128 tile, BK=64, swizzled LDS ----
__global__ __launch_bounds__(256,3) void gemm_qkv(const bf16* __restrict__ xb,
    const bf16* __restrict__ cb, const bf16* __restrict__ wq, const bf16* __restrict__ wk,
    const bf16* __restrict__ wv, const float* __restrict__ bq, const float* __restrict__ bk,
    const float* __restrict__ bv, bf16* __restrict__ qout, bf16* __restrict__ kout,
    bf16* __restrict__ vout){
  const int tid = threadIdx.x, lane = tid & 63, w = tid >> 6;
  const int wr = w >> 1, wc = w & 1, g = lane >> 4, cl = lane & 15;
  const int bz = blockIdx.y, b = bz & 3, mode = bz >> 2;
  const int lb = blockIdx.x;
  int m0, n0;
  if (mode == 2){ m0 = (lb >> 3)*128; n0 = (lb & 7)*128; }
  else          { m0 = (lb / 6)*128;  n0 = (lb % 6)*128; }
  const bf16* A  = (mode==0) ? xb + (size_t)b*T*C : (mode==1) ? cb + (size_t)b*T*C : wv;
  const bf16* Bp = (mode==2) ? cb + (size_t)b*T*C : (mode==0) ? wq : wk;
  const float* bias = (mode==0) ? bq : (mode==1) ? bk : bv;
  const float scale = (mode==0) ? 0.125f : 1.0f;
  __shared__ bf16 lA[128*64], lB[128*64];
  f32x4 acc[4][4] = {};
  const bf16* Ars = A  + (size_t)m0*768;
  const bf16* Brs = Bp + (size_t)n0*768;
  for (int k0 = 0; k0 < 768; k0 += 64){
    __syncthreads();
    #pragma unroll
    for (int rr = 0; rr < 4; ++rr){
      const int u = rr*256 + tid;
      const int row = u >> 3, cc = u & 7;
      const int src = row*768 + k0 + ((cc ^ (row & 7))*8);
      gload16(Ars + src, &lA[(size_t)u*8]);
      gload16(Brs + src, &lB[(size_t)u*8]);
    }
    __syncthreads();
    #pragma unroll
    for (int kh = 0; kh < 2; ++kh){
      short8 af[4], bfr[4];
      #pragma unroll
      for (int mi = 0; mi < 4; ++mi){
        const int row = wr*64 + mi*16 + cl;
        af[mi] = *(const short8*)&lA[row*64 + (((g + kh*4) ^ (row & 7))*8)];
      }
      #pragma unroll
      for (int ni = 0; ni < 4; ++ni){
        const int row = wc*64 + ni*16 + cl;
        bfr[ni] = *(const short8*)&lB[row*64 + (((g + kh*4) ^ (row & 7))*8)];
      }
      __builtin_amdgcn_s_setprio(1);
      #pragma unroll
      for (int mi = 0; mi < 4; ++mi)
        #pragma unroll
        for (int ni = 0; ni < 4; ++ni)
          acc[mi][ni] = mfma16(af[mi], bfr[ni], acc[mi][ni]);
      __builtin_amdgcn_s_setprio(0);
    }
  }
  #pragma unroll
  for (int mi = 0; mi < 4; ++mi){
    const int mB = m0 + wr*64 + mi*16 + g*4;
    #pragma unroll
    for (int ni = 0; ni < 4; ++ni){
      const int n = n0 + wc*64 + ni*16 + cl;
      #pragma unroll
      for (int r = 0; r < 4; ++r){
        const int m = mB + r;
        float v = acc[mi][ni][r];
        if (mode <= 1){
          v = (v + bias[n]) * scale;
          bf16* outp = mode ? kout : qout;
          outp[(size_t)b*(H*T*D) + (size_t)(n >> 6)*(T*D) + (size_t)m*D + (n & 63)] = (bf16)v;
        } else {
          v += bias[m];
          vout[(size_t)b*(C*T) + (size_t)m*T + n] = (bf16)v;
        }
      }
    }
  }
}

// ---- output projection GEMM (f32 out) ----
__global__ __launch_bounds__(256,3) void gemm_o(const bf16* __restrict__ wo,
                                                const bf16* __restrict__ attn,
                                                const float* __restrict__ bias,
                                                float* __restrict__ outp){
  const int tid = threadIdx.x, lane = tid & 63, w = tid >> 6;
  const int wr = w >> 1, wc = w & 1, g = lane >> 4, cl = lane & 15;
  const int b = blockIdx.z;
  const int m0 = blockIdx.x*128, n0 = blockIdx.y*128;
  __shared__ bf16 lA[128*64], lB[128*64];
  f32x4 acc[4][4] = {};
  const bf16* Ars = wo + (size_t)m0*768;
  const bf16* Brs = attn + (size_t)b*T*C + (size_t)n0*768;
  for (int k0 = 0; k0 < 768; k0 += 64){
    __syncthreads();
    #pragma unroll
    for (int rr = 0; rr < 4; ++rr){
      const int u = rr*256 + tid;
      const int row = u >> 3, cc = u & 7;
      const int src = row*768 + k0 + ((cc ^ (row & 7))*8);
      gload16(Ars + src, &lA[(size_t)u*8]);
      gload16(Brs + src, &lB[(size_t)u*8]);
    }
    __syncthreads();
    #pragma unroll
    for (int kh = 0; kh < 2; ++kh){
      short8 af[4], bfr[4];
      #pragma unroll
      for (int mi = 0; mi < 4; ++mi){
        const int row = wr*64 + mi*16 + cl;
        af[mi] = *(const short8*)&lA[row*64 + (((g + kh*4) ^ (row & 7))*8)];
      }
      #pragma unroll
      for (int ni = 0; ni < 4; ++ni){
        const int row = wc*64 + ni*16 + cl;
        bfr[ni] = *(const short8*)&lB[row*64 + (((g + kh*4) ^ (row & 7))*8)];
      }
      __builtin_amdgcn_s_setprio(1);
      #pragma unroll
      for (int mi = 0; mi < 4; ++mi)
        #pragma unroll
        for (int ni = 0; ni < 4; ++ni)
          acc[mi][ni] = mfma16(af[mi], bfr[ni], acc[mi][ni]);
      __builtin_amdgcn_s_setprio(0);
    }
  }
  #pragma unroll
  for (int mi = 0; mi < 4; ++mi){
    const int mB = m0 + wr*64 + mi*16 + g*4;
    #pragma unroll
    for (int ni = 0; ni < 4; ++ni){
      const int n = n0 + wc*64 + ni*16 + cl;
      #pragma unroll
      for (int r = 0; r < 4; ++r){
        const int m = mB + r;
        outp[(size_t)b*(C*T) + (size_t)m*T + n] = acc[mi][ni][r] + bias[m];
      }
    }
  }
}

// ---- fused attention, single-barrier double-buffered pipeline ----
__global__ __launch_bounds__(256,3) void attn_kernel(const bf16* __restrict__ qws,
                                                     const bf16* __restrict__ kws,
                                                     const bf16* __restrict__ vws,
                                                     bf16* __restrict__ aws,
                                                     const float* __restrict__ relk,
                                                     const float* __restrict__ relv){
  const int tid = threadIdx.x, lane = tid & 63, w = tid >> 6;
  const int g = lane >> 4, cl = lane & 15;
  const int i0 = blockIdx.x*64, bh = blockIdx.y;
  const int b = bh / H, h = bh % H;

  __shared__ __align__(16) char smem[54272];
  bf16*  lKV      = (bf16*)smem;              // 4 bufs x 4096 elems: K0,K1,V0,V1(=Q)
  bf16*  lP       = (bf16*)(smem + 32768);    // 64x64
  float* relk_dot = (float*)(smem + 40960);   // 64x21
  float* bandS    = (float*)(smem + 46336);   // 64x21
  __half* logtabH = (__half*)(smem + 51712);  // 1024
  float* m_lds    = (float*)(smem + 53760);   // 64
  float* l_lds    = (float*)(smem + 54016);   // 64
  bf16*  lEmbH    = lP;                       // [21][72] prologue alias
  bf16*  lEV      = lP;                       // [64][40] epilogue alias
  bf16*  lPB      = (bf16*)relk_dot;          // [64][40] epilogue alias
  bf16*  lQ       = lKV + 3*4096;

  const bf16* qg = qws + ((size_t)bh*T + i0)*D;
  const bf16* kg = kws + (size_t)bh*T*D;
  const bf16* vg = vws + ((size_t)b*C + h*D)*T;

  #pragma unroll
  for (int r = 0; r < 2; ++r){
    const int u = r*256 + tid, row = u >> 3, cc = u & 7;
    const int sc8 = (cc ^ (row & 7))*8;
    gload16(qg + row*64 + sc8,          &lQ[(size_t)u*8]);
    gload16(kg + (size_t)row*D + sc8,   &lKV[(size_t)u*8]);
    gload16(vg + (size_t)row*T + sc8,   &lKV[2*4096 + (size_t)u*8]);
  }
  for (int idx = tid; idx < 1024; idx += 256)
    logtabH[idx] = __float2half(__logf(1.0f + (float)idx));
  for (int idx = tid; idx < 21*64; idx += 256)
    lEmbH[(idx >> 6)*72 + (idx & 63)] = (bf16)relk[idx];
  __syncthreads();

  // per-row dot of scaled-Q with each of the 21 rel-k embeddings
  for (int p = tid; p < 64*21; p += 256){
    const int i = p / 21, r = p - i*21;
    float s = 0.f;
    #pragma unroll
    for (int c2 = 0; c2 < 8; ++c2){
      short8 qv = *(const short8*)&lQ[i*64 + ((c2 ^ (i & 7))*8)];
      short8 ev = *(const short8*)&lEmbH[r*72 + c2*8];
      #pragma unroll
      for (int e = 0; e < 8; ++e) s += b2f(qv[e]) * b2f(ev[e]);
    }
    relk_dot[p] = s;
  }
  const int qrow = w*16 + cl;
  const int fq = (qrow ^ (qrow >> 1)) & 7;
  const short8 aq0 = *(const short8*)&lQ[qrow*64 + ((g ^ (qrow & 7))*8)];
  const short8 aq1 = *(const short8*)&lQ[qrow*64 + (((g + 4) ^ (qrow & 7))*8)];
  __syncthreads();   // lQ dead after this point (aliased by V buffer 1)

  float mreg[4] = {-1e30f, -1e30f, -1e30f, -1e30f};
  float lreg[4] = {0.f, 0.f, 0.f, 0.f};
  f32x4 o[4] = {};
  const int ib = w*16 + g*4;

  for (int jt = 0; jt < 16; ++jt){
    const int j0 = jt*64, cur = jt & 1, nxt = cur ^ 1;
    if (jt < 15){
      const int jn = j0 + 64;
      #pragma unroll
      for (int r = 0; r < 2; ++r){
        const int u = r*256 + tid, row = u >> 3, cc = u & 7;
        const int sc8 = (cc ^ (row & 7))*8;
        gload16(kg + (size_t)(jn + row)*D + sc8, &lKV[nxt*4096 + (size_t)u*8]);
        gload16(vg + (size_t)row*T + jn + sc8,   &lKV[(2 + nxt)*4096 + (size_t)u*8]);
      }
    }
    const bf16* Kc = lKV + cur*4096;
    const bf16* Vc = lKV + (2 + cur)*4096;

    f32x4 s[4] = {};
    __builtin_amdgcn_s_setprio(1);
    #pragma unroll
    for (int ni = 0; ni < 4; ++ni){
      const int row = ni*16 + cl;
      short8 b0 = *(const short8*)&Kc[row*64 + ((g ^ (row & 7))*8)];
      s[ni] = mfma16(aq0, b0, s[ni]);
      short8 b1 = *(const short8*)&Kc[row*64 + (((g + 4) ^ (row & 7))*8)];
      s[ni] = mfma16(aq1, b1, s[ni]);
    }
    __builtin_amdgcn_s_setprio(0);

    #pragma unroll
    for (int ni = 0; ni < 4; ++ni){
      const int j = j0 + ni*16 + cl;
      #pragma unroll
      for (int r = 0; r < 4; ++r){
        const int dd = j - (i0 + ib + r);
        const int ad = dd < 0 ? -dd : dd;
        float v = s[ni][r] - __half2float(logtabH[ad]);
        if (ad <= 10){
          v += relk_dot[(ib + r)*21 + dd + 10];
          bandS[(ib + r)*21 + dd + 10] = v;   // raw score for exact band-p later
        }
        s[ni][r] = v;
      }
    }

    #pragma unroll
    for (int r = 0; r < 4; ++r){
      float v = fmaxf(fmaxf(s[0][r], s[1][r]), fmaxf(s[2][r], s[3][r]));
      v = rmax16(v);
      const float mn = fmaxf(mreg[r], v);
      const float sc = __expf(mreg[r] - mn);
      mreg[r] = mn;
      float rs = 0.f;
      #pragma unroll
      for (int ni = 0; ni < 4; ++ni){
        float p = __expf(s[ni][r] - mn);
        s[ni][r] = p; rs += p;
      }
      rs = rsum16(rs);
      lreg[r] = lreg[r]*sc + rs;
      o[0][r] *= sc; o[1][r] *= sc; o[2][r] *= sc; o[3][r] *= sc;
      const int prow = ib + r;
      const int fp = ((prow ^ (prow >> 1)) & 7) << 3;
      #pragma unroll
      for (int ni = 0; ni < 4; ++ni)
        lP[prow*64 + ((ni*16 + cl) ^ fp)] = (bf16)s[ni][r];
    }

    const short8 ap0 = *(const short8*)&lP[qrow*64 + ((g ^ fq)*8)];
    const short8 ap1 = *(const short8*)&lP[qrow*64 + (((g + 4) ^ fq)*8)];
    __builtin_amdgcn_s_setprio(1);
    #pragma unroll
    for (int ni = 0; ni < 4; ++ni){
      const int row = ni*16 + cl;
      short8 b0 = *(const short8*)&Vc[row*64 + ((g ^ (row & 7))*8)];
      o[ni] = mfma16(ap0, b0, o[ni]);
      short8 b1 = *(const short8*)&Vc[row*64 + (((g + 4) ^ (row & 7))*8)];
      o[ni] = mfma16(ap1, b1, o[ni]);
    }
    __builtin_amdgcn_s_setprio(0);
    __syncthreads();   // drains next-tile loads; one barrier per iteration
  }

  if (cl == 0){
    #pragma unroll
    for (int r = 0; r < 4; ++r){ m_lds[ib + r] = mreg[r]; l_lds[ib + r] = lreg[r]; }
  }
  __syncthreads();

  // build EV^T tile (over dead lP) and band-prob tile (over dead relk_dot)
  for (int idx = tid; idx < 64*32; idx += 256){
    const int n = idx >> 5, kk = idx & 31;
    lEV[n*40 + kk] = (kk < 21) ? (bf16)relv[kk*64 + n] : (bf16)0.0f;
  }
  for (int p = tid; p < 64*32; p += 256){
    const int i = p >> 5, dd = p & 31;
    const int j = i0 + i + dd - 10;
    float bp = 0.f;
    if (dd < 21 && j >= 0 && j < T)
      bp = __expf(bandS[i*21 + dd] - m_lds[i]) / l_lds[i];
    lPB[i*40 + dd] = (bf16)bp;
  }
  __syncthreads();

  const short8 apb = *(const short8*)&lPB[qrow*40 + g*8];
  f32x4 ba[4];
  #pragma unroll
  for (int ni = 0; ni < 4; ++ni){
    const int row = ni*16 + cl;
    short8 bev = *(const short8*)&lEV[row*40 + g*8];
    f32x4 z = {};
    ba[ni] = mfma16(apb, bev, z);
  }

  float invl[4];
  #pragma unroll
  for (int r = 0; r < 4; ++r) invl[r] = 1.0f / lreg[r];
  #pragma unroll
  for (int ni = 0; ni < 4; ++ni){
    const int dcol = ni*16 + cl;
    #pragma unroll
    for (int r = 0; r < 4; ++r){
      float v = o[ni][r] * invl[r] + ba[ni][r];
      aws[((size_t)(b*T + i0 + ib + r))*C + h*D + dcol] = (bf16)v;
    }
  }
}

extern "C" void kernel_launch(void* const* d_in, const int* in_sizes, int n_in,
                              void* d_out, int out_size, void* d_ws, size_t ws_size,
                              hipStream_t stream){
  const float* x    = (const float*)d_in[0];
  const float* cin  = (const float*)d_in[1];
  const float* Wq   = (const float*)d_in[2];
  const float* bq   = (const float*)d_in[3];
  const float* Wk   = (const float*)d_in[4];
  const float* bk   = (const float*)d_in[5];
  const float* Wv   = (const float*)d_in[6];
  const float* bv   = (const float*)d_in[7];
  const float* Wo   = (const float*)d_in[8];
  const float* bo   = (const float*)d_in[9];
  const float* relk = (const float*)d_in[10];
  const float* relv = (const float*)d_in[11];

  char* ws = (char*)d_ws;
  constexpr size_t SZ_W = (size_t)768*768*2;     // bf16 weight matrix
  constexpr size_t SZ_T = (size_t)4*1024*768*2;  // bf16 [B,T,C]-sized tensor
  bf16* wq  = (bf16*)(ws + 0*SZ_W);
  bf16* wk  = (bf16*)(ws + 1*SZ_W);
  bf16* wv  = (bf16*)(ws + 2*SZ_W);
  bf16* wo  = (bf16*)(ws + 3*SZ_W);
  bf16* xb  = (bf16*)(ws + 4*SZ_W);
  bf16* cb  = (bf16*)(ws + 4*SZ_W + 1*SZ_T);
  bf16* qws = (bf16*)(ws + 4*SZ_W + 2*SZ_T);
  bf16* kws = (bf16*)(ws + 4*SZ_W + 3*SZ_T);
  bf16* vws = (bf16*)(ws + 4*SZ_W + 4*SZ_T);
  bf16* attn = xb;   // alias: xb is dead after the Q projection

  cvt4_kernel<<<dim3(576,4), 256, 0, stream>>>(Wq, Wk, Wv, Wo, wq, wk, wv, wo);
  transpose_cvt2<<<dim3(16,12,8), 256, 0, stream>>>(x, cin, xb, cb);
  gemm_qkv<<<dim3(48,12), 256, 0, stream>>>(xb, cb, wq, wk, wv, bq, bk, bv, qws, kws, vws);
  attn_kernel<<<dim3(16,48), 256, 0, stream>>>(qws, kws, vws, attn, relk, relv);
  gemm_o<<<dim3(6,8,4), 256, 0, stream>>>(wo, attn, bo, (float*)d_out);
}

// Round 5
// 111.248 us; speedup vs baseline: 2.4250x; 1.2638x over previous
//
#include <hip/hip_runtime.h>
#include <hip/hip_bf16.h>

using bf16 = __hip_bfloat16;
typedef __attribute__((ext_vector_type(8))) short short8;
typedef __attribute__((ext_vector_type(4))) float f32x4;

static constexpr int C = 768, T = 1024, H = 12, D = 64;

__device__ __forceinline__ f32x4 mfma16(short8 a, short8 b, f32x4 c){
  return __builtin_amdgcn_mfma_f32_16x16x32_bf16(a, b, c, 0, 0, 0);
}

__device__ __forceinline__ void gload16(const void* g, void* l){
  void* gv = const_cast<void*>(g);
  __builtin_amdgcn_global_load_lds((__attribute__((address_space(1))) void*)gv,
                                   (__attribute__((address_space(3))) void*)l, 16, 0, 0);
}

__device__ __forceinline__ float b2f(short s){
  unsigned u = ((unsigned)(unsigned short)s) << 16;
  return __builtin_bit_cast(float, u);
}

template<int N>
__device__ __forceinline__ float row_ror(float v){
  return __builtin_bit_cast(float, __builtin_amdgcn_update_dpp(
      0, __builtin_bit_cast(int, v), 0x120 | N, 0xF, 0xF, false));
}
__device__ __forceinline__ float rmax16(float v){
  v = fmaxf(v, row_ror<8>(v)); v = fmaxf(v, row_ror<4>(v));
  v = fmaxf(v, row_ror<2>(v)); v = fmaxf(v, row_ror<1>(v)); return v;
}
__device__ __forceinline__ float rsum16(float v){
  v += row_ror<8>(v); v += row_ror<4>(v);
  v += row_ror<2>(v); v += row_ror<1>(v); return v;
}

// log(1+|x|) via the trans pipe (no LDS table)
__device__ __forceinline__ float log1pabs(float x){
  return __log2f(fabsf(x) + 1.0f) * 0.69314718056f;
}

// ---- 4x f32 -> bf16 weight convert, fused ----
__global__ __launch_bounds__(256) void cvt4_kernel(const float* __restrict__ a,
                                                   const float* __restrict__ b,
                                                   const float* __restrict__ c_,
                                                   const float* __restrict__ d,
                                                   bf16* oa, bf16* ob, bf16* oc, bf16* od){
  const int m = blockIdx.y;
  const float* in = m==0 ? a : m==1 ? b : m==2 ? c_ : d;
  bf16* out = m==0 ? oa : m==1 ? ob : m==2 ? oc : od;
  int i = (blockIdx.x*256 + threadIdx.x)*4;
  float4 v = *(const float4*)(in + i);
  out[i+0] = (bf16)v.x; out[i+1] = (bf16)v.y;
  out[i+2] = (bf16)v.z; out[i+3] = (bf16)v.w;
}

// ---- [B][C][T] f32 -> [B][T][C] bf16, both tensors in one launch ----
__global__ __launch_bounds__(256) void transpose_cvt2(const float* __restrict__ xin,
                                                      const float* __restrict__ cin,
                                                      bf16* __restrict__ xo,
                                                      bf16* __restrict__ co){
  __shared__ float tile[64][65];
  const int z = blockIdx.z, b = z & 3, which = z >> 2;
  const float* in = which ? cin : xin;
  bf16* out = which ? co : xo;
  const int t0 = blockIdx.x*64, c0 = blockIdx.y*64;
  const int u = threadIdx.x & 63, r0 = threadIdx.x >> 6;
  const float* ip = in + ((size_t)b*C + c0)*T + t0;
  #pragma unroll
  for (int i = r0; i < 64; i += 4) tile[i][u] = ip[(size_t)i*T + u];
  __syncthreads();
  bf16* op = out + ((size_t)b*T + t0)*C + c0;
  #pragma unroll
  for (int j = r0; j < 64; j += 4) op[(size_t)j*C + u] = (bf16)tile[u][j];
}

// ---- merged Q/K/V projection GEMM: 128x128 tile, BK=64, swizzled LDS ----
__global__ __launch_bounds__(256,3) void gemm_qkv(const bf16* __restrict__ xb,
    const bf16* __restrict__ cb, const bf16* __restrict__ wq, const bf16* __restrict__ wk,
    const bf16* __restrict__ wv, const float* __restrict__ bq, const float* __restrict__ bk,
    const float* __restrict__ bv, bf16* __restrict__ qout, bf16* __restrict__ kout,
    bf16* __restrict__ vout){
  const int tid = threadIdx.x, lane = tid & 63, w = tid >> 6;
  const int wr = w >> 1, wc = w & 1, g = lane >> 4, cl = lane & 15;
  const int bz = blockIdx.y, b = bz & 3, mode = bz >> 2;
  const int lb = blockIdx.x;
  int m0, n0;
  if (mode == 2){ m0 = (lb >> 3)*128; n0 = (lb & 7)*128; }
  else          { m0 = (lb / 6)*128;  n0 = (lb % 6)*128; }
  const bf16* A  = (mode==0) ? xb + (size_t)b*T*C : (mode==1) ? cb + (size_t)b*T*C : wv;
  const bf16* Bp = (mode==2) ? cb + (size_t)b*T*C : (mode==0) ? wq : wk;
  const float* bias = (mode==0) ? bq : (mode==1) ? bk : bv;
  const float scale = (mode==0) ? 0.125f : 1.0f;
  __shared__ bf16 lA[128*64], lB[128*64];
  f32x4 acc[4][4] = {};
  const bf16* Ars = A  + (size_t)m0*768;
  const bf16* Brs = Bp + (size_t)n0*768;
  for (int k0 = 0; k0 < 768; k0 += 64){
    __syncthreads();
    #pragma unroll
    for (int rr = 0; rr < 4; ++rr){
      const int u = rr*256 + tid;
      const int row = u >> 3, cc = u & 7;
      const int src = row*768 + k0 + ((cc ^ (row & 7))*8);
      gload16(Ars + src, &lA[(size_t)u*8]);
      gload16(Brs + src, &lB[(size_t)u*8]);
    }
    __syncthreads();
    #pragma unroll
    for (int kh = 0; kh < 2; ++kh){
      short8 af[4], bfr[4];
      #pragma unroll
      for (int mi = 0; mi < 4; ++mi){
        const int row = wr*64 + mi*16 + cl;
        af[mi] = *(const short8*)&lA[row*64 + (((g + kh*4) ^ (row & 7))*8)];
      }
      #pragma unroll
      for (int ni = 0; ni < 4; ++ni){
        const int row = wc*64 + ni*16 + cl;
        bfr[ni] = *(const short8*)&lB[row*64 + (((g + kh*4) ^ (row & 7))*8)];
      }
      __builtin_amdgcn_s_setprio(1);
      #pragma unroll
      for (int mi = 0; mi < 4; ++mi)
        #pragma unroll
        for (int ni = 0; ni < 4; ++ni)
          acc[mi][ni] = mfma16(af[mi], bfr[ni], acc[mi][ni]);
      __builtin_amdgcn_s_setprio(0);
    }
  }
  #pragma unroll
  for (int mi = 0; mi < 4; ++mi){
    const int mB = m0 + wr*64 + mi*16 + g*4;
    #pragma unroll
    for (int ni = 0; ni < 4; ++ni){
      const int n = n0 + wc*64 + ni*16 + cl;
      #pragma unroll
      for (int r = 0; r < 4; ++r){
        const int m = mB + r;
        float v = acc[mi][ni][r];
        if (mode <= 1){
          v = (v + bias[n]) * scale;
          bf16* outp = mode ? kout : qout;
          outp[(size_t)b*(H*T*D) + (size_t)(n >> 6)*(T*D) + (size_t)m*D + (n & 63)] = (bf16)v;
        } else {
          v += bias[m];
          vout[(size_t)b*(C*T) + (size_t)m*T + n] = (bf16)v;
        }
      }
    }
  }
}

// ---- output projection GEMM (f32 out) ----
__global__ __launch_bounds__(256,3) void gemm_o(const bf16* __restrict__ wo,
                                                const bf16* __restrict__ attn,
                                                const float* __restrict__ bias,
                                                float* __restrict__ outp){
  const int tid = threadIdx.x, lane = tid & 63, w = tid >> 6;
  const int wr = w >> 1, wc = w & 1, g = lane >> 4, cl = lane & 15;
  const int b = blockIdx.z;
  const int m0 = blockIdx.x*128, n0 = blockIdx.y*128;
  __shared__ bf16 lA[128*64], lB[128*64];
  f32x4 acc[4][4] = {};
  const bf16* Ars = wo + (size_t)m0*768;
  const bf16* Brs = attn + (size_t)b*T*C + (size_t)n0*768;
  for (int k0 = 0; k0 < 768; k0 += 64){
    __syncthreads();
    #pragma unroll
    for (int rr = 0; rr < 4; ++rr){
      const int u = rr*256 + tid;
      const int row = u >> 3, cc = u & 7;
      const int src = row*768 + k0 + ((cc ^ (row & 7))*8);
      gload16(Ars + src, &lA[(size_t)u*8]);
      gload16(Brs + src, &lB[(size_t)u*8]);
    }
    __syncthreads();
    #pragma unroll
    for (int kh = 0; kh < 2; ++kh){
      short8 af[4], bfr[4];
      #pragma unroll
      for (int mi = 0; mi < 4; ++mi){
        const int row = wr*64 + mi*16 + cl;
        af[mi] = *(const short8*)&lA[row*64 + (((g + kh*4) ^ (row & 7))*8)];
      }
      #pragma unroll
      for (int ni = 0; ni < 4; ++ni){
        const int row = wc*64 + ni*16 + cl;
        bfr[ni] = *(const short8*)&lB[row*64 + (((g + kh*4) ^ (row & 7))*8)];
      }
      __builtin_amdgcn_s_setprio(1);
      #pragma unroll
      for (int mi = 0; mi < 4; ++mi)
        #pragma unroll
        for (int ni = 0; ni < 4; ++ni)
          acc[mi][ni] = mfma16(af[mi], bfr[ni], acc[mi][ni]);
      __builtin_amdgcn_s_setprio(0);
    }
  }
  #pragma unroll
  for (int mi = 0; mi < 4; ++mi){
    const int mB = m0 + wr*64 + mi*16 + g*4;
    #pragma unroll
    for (int ni = 0; ni < 4; ++ni){
      const int n = n0 + wc*64 + ni*16 + cl;
      #pragma unroll
      for (int r = 0; r < 4; ++r){
        const int m = mB + r;
        outp[(size_t)b*(C*T) + (size_t)m*T + n] = acc[mi][ni][r] + bias[m];
      }
    }
  }
}

// ---- fused attention, single-barrier double-buffered pipeline,
//      band work only on the 3 diagonal j-tiles, log via trans pipe ----
__global__ __launch_bounds__(256,3) void attn_kernel(const bf16* __restrict__ qws,
                                                     const bf16* __restrict__ kws,
                                                     const bf16* __restrict__ vws,
                                                     bf16* __restrict__ aws,
                                                     const float* __restrict__ relk,
                                                     const float* __restrict__ relv){
  const int tid = threadIdx.x, lane = tid & 63, w = tid >> 6;
  const int g = lane >> 4, cl = lane & 15;
  const int i0 = blockIdx.x*64, bh = blockIdx.y;
  const int b = bh / H, h = bh % H;

  __shared__ __align__(16) char smem[52224];
  bf16*  lKV      = (bf16*)smem;              // 4 bufs x 4096 elems: K0,K1,V0,V1(=Q)
  bf16*  lP       = (bf16*)(smem + 32768);    // 64x64
  float* relk_dot = (float*)(smem + 40960);   // 64x21
  float* bandS    = (float*)(smem + 46336);   // 64x21
  float* m_lds    = (float*)(smem + 51712);   // 64
  float* l_lds    = (float*)(smem + 51968);   // 64
  bf16*  lEmb32   = lP;                       // [32][64] prologue alias (rel-k, padded)
  bf16*  lEV      = lP;                       // [64][40] epilogue alias
  bf16*  lPB      = (bf16*)relk_dot;          // [64][40] epilogue alias
  bf16*  lQ       = lKV + 3*4096;

  const bf16* qg = qws + ((size_t)bh*T + i0)*D;
  const bf16* kg = kws + (size_t)bh*T*D;
  const bf16* vg = vws + ((size_t)b*C + h*D)*T;

  #pragma unroll
  for (int r = 0; r < 2; ++r){
    const int u = r*256 + tid, row = u >> 3, cc = u & 7;
    const int sc8 = (cc ^ (row & 7))*8;
    gload16(qg + row*64 + sc8,          &lQ[(size_t)u*8]);
    gload16(kg + (size_t)row*D + sc8,   &lKV[(size_t)u*8]);
    gload16(vg + (size_t)row*T + sc8,   &lKV[2*4096 + (size_t)u*8]);
  }
  // stage rel-k embeddings as padded 32x64 bf16 MFMA tile (swizzled on write)
  for (int idx = tid; idx < 2048; idx += 256){
    const int row = idx >> 6, col = idx & 63;
    const float v = (row < 21) ? relk[idx] : 0.0f;
    lEmb32[row*64 + (((col >> 3) ^ (row & 7))*8 + (col & 7))] = (bf16)v;
  }
  __syncthreads();

  const int qrow = w*16 + cl;
  const int fq = (qrow ^ (qrow >> 1)) & 7;
  const short8 aq0 = *(const short8*)&lQ[qrow*64 + ((g ^ (qrow & 7))*8)];
  const short8 aq1 = *(const short8*)&lQ[qrow*64 + (((g + 4) ^ (qrow & 7))*8)];
  const int ib = w*16 + g*4;

  // relk_dot[i][r] = qs[i] . rel_k[r] as one 64x32x64 MFMA op
  {
    f32x4 rk[2] = {{}, {}};
    #pragma unroll
    for (int ni = 0; ni < 2; ++ni){
      const int row = ni*16 + cl;
      short8 b0 = *(const short8*)&lEmb32[row*64 + ((g ^ (row & 7))*8)];
      rk[ni] = mfma16(aq0, b0, rk[ni]);
      short8 b1 = *(const short8*)&lEmb32[row*64 + (((g + 4) ^ (row & 7))*8)];
      rk[ni] = mfma16(aq1, b1, rk[ni]);
    }
    #pragma unroll
    for (int ni = 0; ni < 2; ++ni){
      const int col = ni*16 + cl;
      if (col < 21){
        #pragma unroll
        for (int r = 0; r < 4; ++r) relk_dot[(ib + r)*21 + col] = rk[ni][r];
      }
    }
  }
  __syncthreads();   // relk_dot visible; lQ & lEmb32(lP) regions free for reuse

  float mreg[4] = {-1e30f, -1e30f, -1e30f, -1e30f};
  float lreg[4] = {0.f, 0.f, 0.f, 0.f};
  f32x4 o[4] = {};

  for (int jt = 0; jt < 16; ++jt){
    const int j0 = jt*64, cur = jt & 1, nxt = cur ^ 1;
    if (jt < 15){
      const int jn = j0 + 64;
      #pragma unroll
      for (int r = 0; r < 2; ++r){
        const int u = r*256 + tid, row = u >> 3, cc = u & 7;
        const int sc8 = (cc ^ (row & 7))*8;
        gload16(kg + (size_t)(jn + row)*D + sc8, &lKV[nxt*4096 + (size_t)u*8]);
        gload16(vg + (size_t)row*T + jn + sc8,   &lKV[(2 + nxt)*4096 + (size_t)u*8]);
      }
    }
    const bf16* Kc = lKV + cur*4096;
    const bf16* Vc = lKV + (2 + cur)*4096;

    f32x4 s[4] = {};
    __builtin_amdgcn_s_setprio(1);
    #pragma unroll
    for (int ni = 0; ni < 4; ++ni){
      const int row = ni*16 + cl;
      short8 b0 = *(const short8*)&Kc[row*64 + ((g ^ (row & 7))*8)];
      s[ni] = mfma16(aq0, b0, s[ni]);
      short8 b1 = *(const short8*)&Kc[row*64 + (((g + 4) ^ (row & 7))*8)];
      s[ni] = mfma16(aq1, b1, s[ni]);
    }
    __builtin_amdgcn_s_setprio(0);

    const int dj = j0 - i0;
    if (dj == 0 || dj == 64 || dj == -64){
      // diagonal tiles: proximal bias + rel-k band add + raw band score stash
      #pragma unroll
      for (int ni = 0; ni < 4; ++ni){
        const int j = j0 + ni*16 + cl;
        #pragma unroll
        for (int r = 0; r < 4; ++r){
          const int dd = j - (i0 + ib + r);
          const int ad = dd < 0 ? -dd : dd;
          float v = s[ni][r] - log1pabs((float)dd);
          if (ad <= 10){
            v += relk_dot[(ib + r)*21 + dd + 10];
            bandS[(ib + r)*21 + dd + 10] = v;
          }
          s[ni][r] = v;
        }
      }
    } else {
      // off-band tiles: proximal bias only, pure VALU/trans
      #pragma unroll
      for (int ni = 0; ni < 4; ++ni){
        const float fbase = (float)(j0 + ni*16 + cl - i0 - ib);
        #pragma unroll
        for (int r = 0; r < 4; ++r)
          s[ni][r] -= log1pabs(fbase - (float)r);
      }
    }

    #pragma unroll
    for (int r = 0; r < 4; ++r){
      float v = fmaxf(fmaxf(s[0][r], s[1][r]), fmaxf(s[2][r], s[3][r]));
      v = rmax16(v);
      const float mn = fmaxf(mreg[r], v);
      const float sc = __expf(mreg[r] - mn);
      mreg[r] = mn;
      float rs = 0.f;
      #pragma unroll
      for (int ni = 0; ni < 4; ++ni){
        float p = __expf(s[ni][r] - mn);
        s[ni][r] = p; rs += p;
      }
      rs = rsum16(rs);
      lreg[r] = lreg[r]*sc + rs;
      o[0][r] *= sc; o[1][r] *= sc; o[2][r] *= sc; o[3][r] *= sc;
      const int prow = ib + r;
      const int fp = ((prow ^ (prow >> 1)) & 7) << 3;
      #pragma unroll
      for (int ni = 0; ni < 4; ++ni)
        lP[prow*64 + ((ni*16 + cl) ^ fp)] = (bf16)s[ni][r];
    }

    const short8 ap0 = *(const short8*)&lP[qrow*64 + ((g ^ fq)*8)];
    const short8 ap1 = *(const short8*)&lP[qrow*64 + (((g + 4) ^ fq)*8)];
    __builtin_amdgcn_s_setprio(1);
    #pragma unroll
    for (int ni = 0; ni < 4; ++ni){
      const int row = ni*16 + cl;
      short8 b0 = *(const short8*)&Vc[row*64 + ((g ^ (row & 7))*8)];
      o[ni] = mfma16(ap0, b0, o[ni]);
      short8 b1 = *(const short8*)&Vc[row*64 + (((g + 4) ^ (row & 7))*8)];
      o[ni] = mfma16(ap1, b1, o[ni]);
    }
    __builtin_amdgcn_s_setprio(0);
    __syncthreads();   // drains next-tile loads; one barrier per iteration
  }

  if (cl == 0){
    #pragma unroll
    for (int r = 0; r < 4; ++r){ m_lds[ib + r] = mreg[r]; l_lds[ib + r] = lreg[r]; }
  }
  __syncthreads();

  // build EV^T tile (over dead lP) and band-prob tile (over dead relk_dot)
  for (int idx = tid; idx < 64*32; idx += 256){
    const int n = idx >> 5, kk = idx & 31;
    lEV[n*40 + kk] = (kk < 21) ? (bf16)relv[kk*64 + n] : (bf16)0.0f;
  }
  for (int p = tid; p < 64*32; p += 256){
    const int i = p >> 5, dd = p & 31;
    const int j = i0 + i + dd - 10;
    float bp = 0.f;
    if (dd < 21 && j >= 0 && j < T)
      bp = __expf(bandS[i*21 + dd] - m_lds[i]) / l_lds[i];
    lPB[i*40 + dd] = (bf16)bp;
  }
  __syncthreads();

  const short8 apb = *(const short8*)&lPB[qrow*40 + g*8];
  f32x4 ba[4];
  #pragma unroll
  for (int ni = 0; ni < 4; ++ni){
    const int row = ni*16 + cl;
    short8 bev = *(const short8*)&lEV[row*40 + g*8];
    f32x4 z = {};
    ba[ni] = mfma16(apb, bev, z);
  }

  float invl[4];
  #pragma unroll
  for (int r = 0; r < 4; ++r) invl[r] = 1.0f / lreg[r];
  #pragma unroll
  for (int ni = 0; ni < 4; ++ni){
    const int dcol = ni*16 + cl;
    #pragma unroll
    for (int r = 0; r < 4; ++r){
      float v = o[ni][r] * invl[r] + ba[ni][r];
      aws[((size_t)(b*T + i0 + ib + r))*C + h*D + dcol] = (bf16)v;
    }
  }
}

extern "C" void kernel_launch(void* const* d_in, const int* in_sizes, int n_in,
                              void* d_out, int out_size, void* d_ws, size_t ws_size,
                              hipStream_t stream){
  const float* x    = (const float*)d_in[0];
  const float* cin  = (const float*)d_in[1];
  const float* Wq   = (const float*)d_in[2];
  const float* bq   = (const float*)d_in[3];
  const float* Wk   = (const float*)d_in[4];
  const float* bk   = (const float*)d_in[5];
  const float* Wv   = (const float*)d_in[6];
  const float* bv   = (const float*)d_in[7];
  const float* Wo   = (const float*)d_in[8];
  const float* bo   = (const float*)d_in[9];
  const float* relk = (const float*)d_in[10];
  const float* relv = (const float*)d_in[11];

  char* ws = (char*)d_ws;
  constexpr size_t SZ_W = (size_t)768*768*2;     // bf16 weight matrix
  constexpr size_t SZ_T = (size_t)4*1024*768*2;  // bf16 [B,T,C]-sized tensor
  bf16* wq  = (bf16*)(ws + 0*SZ_W);
  bf16* wk  = (bf16*)(ws + 1*SZ_W);
  bf16* wv  = (bf16*)(ws + 2*SZ_W);
  bf16* wo  = (bf16*)(ws + 3*SZ_W);
  bf16* xb  = (bf16*)(ws + 4*SZ_W);
  bf16* cb  = (bf16*)(ws + 4*SZ_W + 1*SZ_T);
  bf16* qws = (bf16*)(ws + 4*SZ_W + 2*SZ_T);
  bf16* kws = (bf16*)(ws + 4*SZ_W + 3*SZ_T);
  bf16* vws = (bf16*)(ws + 4*SZ_W + 4*SZ_T);
  bf16* attn = xb;   // alias: xb is dead after the Q projection

  cvt4_kernel<<<dim3(576,4), 256, 0, stream>>>(Wq, Wk, Wv, Wo, wq, wk, wv, wo);
  transpose_cvt2<<<dim3(16,12,8), 256, 0, stream>>>(x, cin, xb, cb);
  gemm_qkv<<<dim3(48,12), 256, 0, stream>>>(xb, cb, wq, wk, wv, bq, bk, bv, qws, kws, vws);
  attn_kernel<<<dim3(16,48), 256, 0, stream>>>(qws, kws, vws, attn, relk, relv);
  gemm_o<<<dim3(6,8,4), 256, 0, stream>>>(wo, attn, bo, (float*)d_out);
}

// Round 6
// 100.720 us; speedup vs baseline: 2.6784x; 1.1045x over previous
//
#include <hip/hip_runtime.h>
#include <hip/hip_bf16.h>

using bf16 = __hip_bfloat16;
typedef __attribute__((ext_vector_type(8))) short short8;
typedef __attribute__((ext_vector_type(4))) float f32x4;

static constexpr int C = 768, T = 1024, H = 12, D = 64;

__device__ __forceinline__ f32x4 mfma16(short8 a, short8 b, f32x4 c){
  return __builtin_amdgcn_mfma_f32_16x16x32_bf16(a, b, c, 0, 0, 0);
}

__device__ __forceinline__ void gload16(const void* g, void* l){
  void* gv = const_cast<void*>(g);
  __builtin_amdgcn_global_load_lds((__attribute__((address_space(1))) void*)gv,
                                   (__attribute__((address_space(3))) void*)l, 16, 0, 0);
}

__device__ __forceinline__ float b2f(short s){
  unsigned u = ((unsigned)(unsigned short)s) << 16;
  return __builtin_bit_cast(float, u);
}

// pack two f32 -> one u32 of 2 bf16 (lo = a, hi = b)
__device__ __forceinline__ int cvtpk(float a, float b){
  int r;
  asm("v_cvt_pk_bf16_f32 %0, %1, %2" : "=v"(r) : "v"(a), "v"(b));
  return r;
}

union PkU { int i[4]; short8 v; };

// ---- 4x f32 -> bf16 weight convert, fused ----
__global__ __launch_bounds__(256) void cvt4_kernel(const float* __restrict__ a,
                                                   const float* __restrict__ b,
                                                   const float* __restrict__ c_,
                                                   const float* __restrict__ d,
                                                   bf16* oa, bf16* ob, bf16* oc, bf16* od){
  const int m = blockIdx.y;
  const float* in = m==0 ? a : m==1 ? b : m==2 ? c_ : d;
  bf16* out = m==0 ? oa : m==1 ? ob : m==2 ? oc : od;
  int i = (blockIdx.x*256 + threadIdx.x)*4;
  float4 v = *(const float4*)(in + i);
  out[i+0] = (bf16)v.x; out[i+1] = (bf16)v.y;
  out[i+2] = (bf16)v.z; out[i+3] = (bf16)v.w;
}

// ---- [B][C][T] f32 -> [B][T][C] bf16, both tensors in one launch ----
__global__ __launch_bounds__(256) void transpose_cvt2(const float* __restrict__ xin,
                                                      const float* __restrict__ cin,
                                                      bf16* __restrict__ xo,
                                                      bf16* __restrict__ co){
  __shared__ float tile[64][65];
  const int z = blockIdx.z, b = z & 3, which = z >> 2;
  const float* in = which ? cin : xin;
  bf16* out = which ? co : xo;
  const int t0 = blockIdx.x*64, c0 = blockIdx.y*64;
  const int u = threadIdx.x & 63, r0 = threadIdx.x >> 6;
  const float* ip = in + ((size_t)b*C + c0)*T + t0;
  #pragma unroll
  for (int i = r0; i < 64; i += 4) tile[i][u] = ip[(size_t)i*T + u];
  __syncthreads();
  bf16* op = out + ((size_t)b*T + t0)*C + c0;
  #pragma unroll
  for (int j = r0; j < 64; j += 4) op[(size_t)j*C + u] = (bf16)tile[u][j];
}

// ---- merged Q/K/V projection GEMM: 128x128 tile, BK=64, swizzled LDS ----
// Q is scaled by 0.125 * log2(e) so attention scores live in log2 domain.
__global__ __launch_bounds__(256,3) void gemm_qkv(const bf16* __restrict__ xb,
    const bf16* __restrict__ cb, const bf16* __restrict__ wq, const bf16* __restrict__ wk,
    const bf16* __restrict__ wv, const float* __restrict__ bq, const float* __restrict__ bk,
    const float* __restrict__ bv, bf16* __restrict__ qout, bf16* __restrict__ kout,
    bf16* __restrict__ vout){
  const int tid = threadIdx.x, lane = tid & 63, w = tid >> 6;
  const int wr = w >> 1, wc = w & 1, g = lane >> 4, cl = lane & 15;
  const int bz = blockIdx.y, b = bz & 3, mode = bz >> 2;
  const int lb = blockIdx.x;
  int m0, n0;
  if (mode == 2){ m0 = (lb >> 3)*128; n0 = (lb & 7)*128; }
  else          { m0 = (lb / 6)*128;  n0 = (lb % 6)*128; }
  const bf16* A  = (mode==0) ? xb + (size_t)b*T*C : (mode==1) ? cb + (size_t)b*T*C : wv;
  const bf16* Bp = (mode==2) ? cb + (size_t)b*T*C : (mode==0) ? wq : wk;
  const float* bias = (mode==0) ? bq : (mode==1) ? bk : bv;
  const float scale = (mode==0) ? 0.125f*1.44269504088896f : 1.0f;
  __shared__ bf16 lA[128*64], lB[128*64];
  f32x4 acc[4][4] = {};
  const bf16* Ars = A  + (size_t)m0*768;
  const bf16* Brs = Bp + (size_t)n0*768;
  for (int k0 = 0; k0 < 768; k0 += 64){
    __syncthreads();
    #pragma unroll
    for (int rr = 0; rr < 4; ++rr){
      const int u = rr*256 + tid;
      const int row = u >> 3, cc = u & 7;
      const int src = row*768 + k0 + ((cc ^ (row & 7))*8);
      gload16(Ars + src, &lA[(size_t)u*8]);
      gload16(Brs + src, &lB[(size_t)u*8]);
    }
    __syncthreads();
    #pragma unroll
    for (int kh = 0; kh < 2; ++kh){
      short8 af[4], bfr[4];
      #pragma unroll
      for (int mi = 0; mi < 4; ++mi){
        const int row = wr*64 + mi*16 + cl;
        af[mi] = *(const short8*)&lA[row*64 + (((g + kh*4) ^ (row & 7))*8)];
      }
      #pragma unroll
      for (int ni = 0; ni < 4; ++ni){
        const int row = wc*64 + ni*16 + cl;
        bfr[ni] = *(const short8*)&lB[row*64 + (((g + kh*4) ^ (row & 7))*8)];
      }
      __builtin_amdgcn_s_setprio(1);
      #pragma unroll
      for (int mi = 0; mi < 4; ++mi)
        #pragma unroll
        for (int ni = 0; ni < 4; ++ni)
          acc[mi][ni] = mfma16(af[mi], bfr[ni], acc[mi][ni]);
      __builtin_amdgcn_s_setprio(0);
    }
  }
  #pragma unroll
  for (int mi = 0; mi < 4; ++mi){
    const int mB = m0 + wr*64 + mi*16 + g*4;
    #pragma unroll
    for (int ni = 0; ni < 4; ++ni){
      const int n = n0 + wc*64 + ni*16 + cl;
      #pragma unroll
      for (int r = 0; r < 4; ++r){
        const int m = mB + r;
        float v = acc[mi][ni][r];
        if (mode <= 1){
          v = (v + bias[n]) * scale;
          bf16* outp = mode ? kout : qout;
          outp[(size_t)b*(H*T*D) + (size_t)(n >> 6)*(T*D) + (size_t)m*D + (n & 63)] = (bf16)v;
        } else {
          v += bias[m];
          vout[(size_t)b*(C*T) + (size_t)m*T + n] = (bf16)v;
        }
      }
    }
  }
}

// ---- output projection GEMM (f32 out) ----
__global__ __launch_bounds__(256,3) void gemm_o(const bf16* __restrict__ wo,
                                                const bf16* __restrict__ attn,
                                                const float* __restrict__ bias,
                                                float* __restrict__ outp){
  const int tid = threadIdx.x, lane = tid & 63, w = tid >> 6;
  const int wr = w >> 1, wc = w & 1, g = lane >> 4, cl = lane & 15;
  const int b = blockIdx.z;
  const int m0 = blockIdx.x*128, n0 = blockIdx.y*128;
  __shared__ bf16 lA[128*64], lB[128*64];
  f32x4 acc[4][4] = {};
  const bf16* Ars = wo + (size_t)m0*768;
  const bf16* Brs = attn + (size_t)b*T*C + (size_t)n0*768;
  for (int k0 = 0; k0 < 768; k0 += 64){
    __syncthreads();
    #pragma unroll
    for (int rr = 0; rr < 4; ++rr){
      const int u = rr*256 + tid;
      const int row = u >> 3, cc = u & 7;
      const int src = row*768 + k0 + ((cc ^ (row & 7))*8);
      gload16(Ars + src, &lA[(size_t)u*8]);
      gload16(Brs + src, &lB[(size_t)u*8]);
    }
    __syncthreads();
    #pragma unroll
    for (int kh = 0; kh < 2; ++kh){
      short8 af[4], bfr[4];
      #pragma unroll
      for (int mi = 0; mi < 4; ++mi){
        const int row = wr*64 + mi*16 + cl;
        af[mi] = *(const short8*)&lA[row*64 + (((g + kh*4) ^ (row & 7))*8)];
      }
      #pragma unroll
      for (int ni = 0; ni < 4; ++ni){
        const int row = wc*64 + ni*16 + cl;
        bfr[ni] = *(const short8*)&lB[row*64 + (((g + kh*4) ^ (row & 7))*8)];
      }
      __builtin_amdgcn_s_setprio(1);
      #pragma unroll
      for (int mi = 0; mi < 4; ++mi)
        #pragma unroll
        for (int ni = 0; ni < 4; ++ni)
          acc[mi][ni] = mfma16(af[mi], bfr[ni], acc[mi][ni]);
      __builtin_amdgcn_s_setprio(0);
    }
  }
  #pragma unroll
  for (int mi = 0; mi < 4; ++mi){
    const int mB = m0 + wr*64 + mi*16 + g*4;
    #pragma unroll
    for (int ni = 0; ni < 4; ++ni){
      const int n = n0 + wc*64 + ni*16 + cl;
      #pragma unroll
      for (int r = 0; r < 4; ++r){
        const int m = mB + r;
        outp[(size_t)b*(C*T) + (size_t)m*T + n] = acc[mi][ni][r] + bias[m];
      }
    }
  }
}

// ---- fused attention, transposed-P structure: S^T = mfma(K,Q); P lane-local;
//      sigma-permuted K staging makes PV B-frag lane-local (no LDS P round-trip).
//      All score math in log2 domain (Q pre-scaled by log2 e). ----
__global__ __launch_bounds__(256,3) void attn_kernel(const bf16* __restrict__ qws,
                                                     const bf16* __restrict__ kws,
                                                     const bf16* __restrict__ vws,
                                                     bf16* __restrict__ aws,
                                                     const float* __restrict__ relk,
                                                     const float* __restrict__ relv){
  const int tid = threadIdx.x, lane = tid & 63, w = tid >> 6;
  const int g = lane >> 4, cl = lane & 15;
  const int i0 = blockIdx.x*64, bh = blockIdx.y;
  const int b = bh / H, h = bh % H;
  const int ql = w*16 + cl;            // this lane's q row (block-local)
  const int qt = i0 + ql;              // global q row

  __shared__ __align__(16) char smem[40960];
  bf16*  lKV   = (bf16*)smem;                  // 4 bufs x 4096: K0,K1,V0,V1(=Q)
  float* bandS = (float*)(smem + 32768);       // [64][21] raw band scores (log2)
  bf16*  relkD = (bf16*)(smem + 38144);        // [64][22] per-row rel-k dots
  bf16*  lEmb32 = lKV + 4096;                  // [32][64] prologue alias (buf1)
  bf16*  lEV    = lKV;                         // [64][32] epilogue alias (buf0)
  bf16*  lQ     = lKV + 3*4096;                // buf3

  const bf16* qg = qws + ((size_t)bh*T + i0)*D;
  const bf16* kg = kws + (size_t)bh*T*D;
  const bf16* vg = vws + ((size_t)b*C + h*D)*T;

  // staging offsets (per lane, hoisted). K rows permuted by sigma so that a
  // lane's 16 S^T values form two 8-consecutive-k runs for the PV B-fragment.
  int kOff[2], vOff[2], qOff[2], dst[2];
  #pragma unroll
  for (int r = 0; r < 2; ++r){
    const int u = r*256 + tid, L = u >> 3, cc = u & 7;
    const int sc8 = (cc ^ (L & 7))*8;
    const int sig = (((L>>4)&1)<<5) | (((L>>2)&3)<<3) | (((L>>5)&1)<<2) | (L&3);
    kOff[r] = sig*64 + sc8;
    vOff[r] = L*T + sc8;
    qOff[r] = L*64 + sc8;
    dst[r]  = u*8;
  }

  #pragma unroll
  for (int r = 0; r < 2; ++r){
    gload16(qg + qOff[r], &lQ[dst[r]]);
    gload16(kg + kOff[r], &lKV[dst[r]]);
    gload16(vg + vOff[r], &lKV[2*4096 + dst[r]]);
  }
  // stage rel-k embeddings as padded 32x64 bf16 tile (chunk-swizzled)
  for (int idx = tid; idx < 2048; idx += 256){
    const int row = idx >> 6, col = idx & 63;
    const float v = (row < 21) ? relk[idx] : 0.0f;
    lEmb32[row*64 + (((col >> 3) ^ (row & 7))*8) + (col & 7)] = (bf16)v;
  }
  __syncthreads();

  const short8 aq0 = *(const short8*)&lQ[ql*64 + ((g ^ (ql & 7))*8)];
  const short8 aq1 = *(const short8*)&lQ[ql*64 + (((g + 4) ^ (ql & 7))*8)];

  // relk_dot via swapped MFMA: R^T[r][q], lane holds r = 16*ni2 + 4g + rr
  #pragma unroll
  for (int ni2 = 0; ni2 < 2; ++ni2){
    const int row = ni2*16 + cl;
    short8 e0 = *(const short8*)&lEmb32[row*64 + ((g ^ (row & 7))*8)];
    short8 e1 = *(const short8*)&lEmb32[row*64 + (((g + 4) ^ (row & 7))*8)];
    f32x4 rk = {};
    rk = mfma16(e0, aq0, rk);
    rk = mfma16(e1, aq1, rk);
    #pragma unroll
    for (int rr = 0; rr < 4; ++rr){
      const int ridx = ni2*16 + 4*g + rr;
      if (ridx < 21) relkD[ql*22 + ridx] = (bf16)rk[rr];
    }
  }
  __syncthreads();   // relkD visible; buf1 (lEmb32) free for K prefetch

  float mreg = -1e30f, lreg = 0.f;
  f32x4 o[4] = {};
  const int koffA[4] = {8*g, 32 + 8*g, 4 + 8*g, 36 + 8*g};

  for (int jt = 0; jt < 16; ++jt){
    const int j0 = jt*64, cur = jt & 1, nxt = cur ^ 1;
    if (jt < 15){
      const int jn = j0 + 64;
      #pragma unroll
      for (int r = 0; r < 2; ++r){
        gload16(kg + jn*64 + kOff[r], &lKV[nxt*4096 + dst[r]]);
        gload16(vg + jn + vOff[r],    &lKV[(2 + nxt)*4096 + dst[r]]);
      }
    }
    const bf16* Kc = lKV + cur*4096;
    const bf16* Vc = lKV + (2 + cur)*4096;

    // S^T tiles: lane holds 16 scores for its own q row
    f32x4 s[4] = {};
    __builtin_amdgcn_s_setprio(1);
    #pragma unroll
    for (int ni = 0; ni < 4; ++ni){
      const int row = ni*16 + cl;
      short8 k0f = *(const short8*)&Kc[row*64 + ((g ^ (row & 7))*8)];
      s[ni] = mfma16(k0f, aq0, s[ni]);
      short8 k1f = *(const short8*)&Kc[row*64 + (((g + 4) ^ (row & 7))*8)];
      s[ni] = mfma16(k1f, aq1, s[ni]);
    }
    __builtin_amdgcn_s_setprio(0);

    const int dj = j0 - i0;
    if (dj == 0 || dj == 64 || dj == -64){
      #pragma unroll
      for (int ni = 0; ni < 4; ++ni){
        const int ibase = j0 + koffA[ni] - qt;
        #pragma unroll
        for (int r = 0; r < 4; ++r){
          const int dd = ibase + r;
          float v = s[ni][r] - __log2f(fabsf((float)dd) + 1.0f);
          if ((unsigned)(dd + 10) <= 20u){
            v += b2f(*(const short*)&relkD[ql*22 + dd + 10]);
            bandS[ql*21 + dd + 10] = v;
          }
          s[ni][r] = v;
        }
      }
    } else {
      #pragma unroll
      for (int ni = 0; ni < 4; ++ni){
        const float fb = (float)(j0 + koffA[ni] - qt);
        #pragma unroll
        for (int r = 0; r < 4; ++r)
          s[ni][r] -= __log2f(fabsf(fb + (float)r) + 1.0f);
      }
    }

    // lane-local online softmax (log2 domain)
    float m0 = fmaxf(fmaxf(s[0][0], s[0][1]), fmaxf(s[0][2], s[0][3]));
    float m1 = fmaxf(fmaxf(s[1][0], s[1][1]), fmaxf(s[1][2], s[1][3]));
    float m2 = fmaxf(fmaxf(s[2][0], s[2][1]), fmaxf(s[2][2], s[2][3]));
    float m3 = fmaxf(fmaxf(s[3][0], s[3][1]), fmaxf(s[3][2], s[3][3]));
    float mx = fmaxf(fmaxf(m0, m1), fmaxf(m2, m3));
    mx = fmaxf(mx, __shfl_xor(mx, 16));
    mx = fmaxf(mx, __shfl_xor(mx, 32));
    const float mn = fmaxf(mreg, mx);
    if (!__all(mn == mreg)){
      const float sc = __builtin_amdgcn_exp2f(mreg - mn);
      lreg *= sc;
      #pragma unroll
      for (int di = 0; di < 4; ++di)
        #pragma unroll
        for (int r = 0; r < 4; ++r) o[di][r] *= sc;
      mreg = mn;
    }
    float rs = 0.f;
    #pragma unroll
    for (int ni = 0; ni < 4; ++ni)
      #pragma unroll
      for (int r = 0; r < 4; ++r){
        float p = __builtin_amdgcn_exp2f(s[ni][r] - mreg);
        s[ni][r] = p; rs += p;
      }
    rs += __shfl_xor(rs, 16);
    rs += __shfl_xor(rs, 32);
    lreg += rs;

    // pack P in-register: nb=0 frag = {ni0, ni2}, nb=1 frag = {ni1, ni3}
    PkU bf0, bf1;
    bf0.i[0] = cvtpk(s[0][0], s[0][1]); bf0.i[1] = cvtpk(s[0][2], s[0][3]);
    bf0.i[2] = cvtpk(s[2][0], s[2][1]); bf0.i[3] = cvtpk(s[2][2], s[2][3]);
    bf1.i[0] = cvtpk(s[1][0], s[1][1]); bf1.i[1] = cvtpk(s[1][2], s[1][3]);
    bf1.i[2] = cvtpk(s[3][0], s[3][1]); bf1.i[3] = cvtpk(s[3][2], s[3][3]);

    __builtin_amdgcn_s_setprio(1);
    #pragma unroll
    for (int di = 0; di < 4; ++di){
      const int vrow = di*16 + cl;
      short8 a0 = *(const short8*)&Vc[vrow*64 + ((g ^ (vrow & 7))*8)];
      o[di] = mfma16(a0, bf0.v, o[di]);
      short8 a1 = *(const short8*)&Vc[vrow*64 + (((g + 4) ^ (vrow & 7))*8)];
      o[di] = mfma16(a1, bf1.v, o[di]);
    }
    __builtin_amdgcn_s_setprio(0);
    __syncthreads();   // drains next-tile loads; one barrier per iteration
  }

  // epilogue: rel-v band contribution via MFMA, fully register-fed B operand
  for (int idx = tid; idx < 2048; idx += 256){
    const int d = idx >> 5, c = idx & 31;
    const float v = (c < 21) ? relv[c*64 + d] : 0.0f;
    lEV[d*32 + (((c >> 3) ^ ((d >> 2) & 3))*8) + (c & 7)] = (bf16)v;
  }
  __syncthreads();

  const float invl = 1.0f / lreg;
  float pb[8];
  #pragma unroll
  for (int e = 0; e < 8; ++e){
    const int ddi = 8*g + e;
    float pv = 0.f;
    if (ddi < 21){
      const int j = qt + ddi - 10;
      if (j >= 0 && j < T)
        pv = __builtin_amdgcn_exp2f(bandS[ql*21 + ddi] - mreg) * invl;
    }
    pb[e] = pv;
  }
  PkU bfE;
  bfE.i[0] = cvtpk(pb[0], pb[1]); bfE.i[1] = cvtpk(pb[2], pb[3]);
  bfE.i[2] = cvtpk(pb[4], pb[5]); bfE.i[3] = cvtpk(pb[6], pb[7]);

  bf16* outp = aws + (size_t)(b*T + qt)*C + h*64;
  #pragma unroll
  for (int di = 0; di < 4; ++di){
    const int arow = di*16 + cl;
    short8 aE = *(const short8*)&lEV[arow*32 + ((g ^ ((arow >> 2) & 3))*8)];
    f32x4 z = {};
    f32x4 ba = mfma16(aE, bfE.v, z);
    const int p0 = cvtpk(o[di][0]*invl + ba[0], o[di][1]*invl + ba[1]);
    const int p1 = cvtpk(o[di][2]*invl + ba[2], o[di][3]*invl + ba[3]);
    *(int2*)(outp + di*16 + 4*g) = make_int2(p0, p1);
  }
}

extern "C" void kernel_launch(void* const* d_in, const int* in_sizes, int n_in,
                              void* d_out, int out_size, void* d_ws, size_t ws_size,
                              hipStream_t stream){
  const float* x    = (const float*)d_in[0];
  const float* cin  = (const float*)d_in[1];
  const float* Wq   = (const float*)d_in[2];
  const float* bq   = (const float*)d_in[3];
  const float* Wk   = (const float*)d_in[4];
  const float* bk   = (const float*)d_in[5];
  const float* Wv   = (const float*)d_in[6];
  const float* bv   = (const float*)d_in[7];
  const float* Wo   = (const float*)d_in[8];
  const float* bo   = (const float*)d_in[9];
  const float* relk = (const float*)d_in[10];
  const float* relv = (const float*)d_in[11];

  char* ws = (char*)d_ws;
  constexpr size_t SZ_W = (size_t)768*768*2;     // bf16 weight matrix
  constexpr size_t SZ_T = (size_t)4*1024*768*2;  // bf16 [B,T,C]-sized tensor
  bf16* wq  = (bf16*)(ws + 0*SZ_W);
  bf16* wk  = (bf16*)(ws + 1*SZ_W);
  bf16* wv  = (bf16*)(ws + 2*SZ_W);
  bf16* wo  = (bf16*)(ws + 3*SZ_W);
  bf16* xb  = (bf16*)(ws + 4*SZ_W);
  bf16* cb  = (bf16*)(ws + 4*SZ_W + 1*SZ_T);
  bf16* qws = (bf16*)(ws + 4*SZ_W + 2*SZ_T);
  bf16* kws = (bf16*)(ws + 4*SZ_W + 3*SZ_T);
  bf16* vws = (bf16*)(ws + 4*SZ_W + 4*SZ_T);
  bf16* attn = xb;   // alias: xb is dead after the Q projection

  cvt4_kernel<<<dim3(576,4), 256, 0, stream>>>(Wq, Wk, Wv, Wo, wq, wk, wv, wo);
  transpose_cvt2<<<dim3(16,12,8), 256, 0, stream>>>(x, cin, xb, cb);
  gemm_qkv<<<dim3(48,12), 256, 0, stream>>>(xb, cb, wq, wk, wv, bq, bk, bv, qws, kws, vws);
  attn_kernel<<<dim3(16,48), 256, 0, stream>>>(qws, kws, vws, attn, relk, relv);
  gemm_o<<<dim3(6,8,4), 256, 0, stream>>>(wo, attn, bo, (float*)d_out);
}